// Round 14
// baseline (261.064 us; speedup 1.0000x reference)
//
#include <hip/hip_runtime.h>
#include <math.h>

#define D 512
#define H 2048
#define E 8
#define NTOK 8192
#define PTMAX 17408   // capacity of pad_tok/pad_w arrays (rows)

typedef __attribute__((ext_vector_type(8))) short bf16x8;
typedef __attribute__((ext_vector_type(4))) float f32x4;

__device__ __forceinline__ short f2b(float v) {
    unsigned u = __float_as_uint(v);
    unsigned r = (u + 0x7FFFu + ((u >> 16) & 1u)) >> 16;  // RNE
    return (short)r;
}
__device__ __forceinline__ float b2f(short v) {
    unsigned u = ((unsigned)(unsigned short)v) << 16;
    return __uint_as_float(u);
}
__device__ __forceinline__ float gelu_exact(float v) {
    return 0.5f * v * (1.0f + erff(v * 0.70710678118654752f));
}
// tanh-form gelu via HW exp: max |err| ~1e-3 << bf16-h quantization.
__device__ __forceinline__ float gelu_fast(float v) {
    float u2 = -1.5957691216f * (v + 0.044715f * v * v * v);
    return v / (1.f + __expf(u2));
}
// async global->LDS, 16B per lane; LDS dest is wave-uniform base + lane*16
__device__ __forceinline__ void gll16(const void* g, void* l) {
    __builtin_amdgcn_global_load_lds(
        (const __attribute__((address_space(1))) void*)g,
        (__attribute__((address_space(3))) void*)l, 16, 0, 0);
}
// padded (128-aligned) prefix over cnt[]
__device__ __forceinline__ void seg_of(const int* cnt, int e, int& s0, int& P) {
    int o = 0;
#pragma unroll
    for (int i = 0; i < E; ++i) {
        int p = (cnt[i] + 127) & ~127;
        if (i < e) o += p;
        if (i == e) P = p;
    }
    s0 = o;
}

// ---------------- Router score: wave-per-token, NO global atomics --------------
__global__ __launch_bounds__(256) void router_score(
    const float* __restrict__ x, const float* __restrict__ ts,
    const float* __restrict__ gw, const float* __restrict__ gb,
    int* __restrict__ sel, float2* __restrict__ wsel,
    short* __restrict__ xbf)
{
    int wave = threadIdx.x >> 6, lane = threadIdx.x & 63;
    int t = blockIdx.x * 4 + wave;

    const float* xr = x + (size_t)t * D + lane * 8;
    const float* tr = ts + (size_t)t * D + lane * 8;
    float4 xa = *reinterpret_cast<const float4*>(xr);
    float4 xb = *reinterpret_cast<const float4*>(xr + 4);
    float4 ta = *reinterpret_cast<const float4*>(tr);
    float4 tb = *reinterpret_cast<const float4*>(tr + 4);

    bf16x8 o;
    o[0] = f2b(xa.x); o[1] = f2b(xa.y); o[2] = f2b(xa.z); o[3] = f2b(xa.w);
    o[4] = f2b(xb.x); o[5] = f2b(xb.y); o[6] = f2b(xb.z); o[7] = f2b(xb.w);
    *reinterpret_cast<bf16x8*>(xbf + (size_t)t * D + lane * 8) = o;

    float v[8] = {xa.x + ta.x, xa.y + ta.y, xa.z + ta.z, xa.w + ta.w,
                  xb.x + tb.x, xb.y + tb.y, xb.z + tb.z, xb.w + tb.w};
    float acc[E];
#pragma unroll
    for (int e2 = 0; e2 < E; ++e2) acc[e2] = 0.f;
#pragma unroll
    for (int i = 0; i < 8; ++i) {
        const float4* gr = reinterpret_cast<const float4*>(gw + (size_t)(lane * 8 + i) * E);
        float4 g0 = gr[0], g1 = gr[1];
        acc[0] += v[i] * g0.x; acc[1] += v[i] * g0.y; acc[2] += v[i] * g0.z; acc[3] += v[i] * g0.w;
        acc[4] += v[i] * g1.x; acc[5] += v[i] * g1.y; acc[6] += v[i] * g1.z; acc[7] += v[i] * g1.w;
    }
#pragma unroll
    for (int m = 32; m; m >>= 1) {
#pragma unroll
        for (int e2 = 0; e2 < E; ++e2) acc[e2] += __shfl_xor(acc[e2], m);
    }
    if (lane == 0) {
        float p[E]; float mx;
#pragma unroll
        for (int e2 = 0; e2 < E; ++e2) p[e2] = acc[e2] + gb[e2];
        mx = p[0];
#pragma unroll
        for (int e2 = 1; e2 < E; ++e2) mx = fmaxf(mx, p[e2]);
        float s = 0.f;
#pragma unroll
        for (int e2 = 0; e2 < E; ++e2) { p[e2] = expf(p[e2] - mx); s += p[e2]; }
        float inv = 1.f / s;
        int i0 = 0; float v0 = p[0];
#pragma unroll
        for (int e2 = 1; e2 < E; ++e2) if (p[e2] > v0) { v0 = p[e2]; i0 = e2; }
        int i1 = (i0 == 0) ? 1 : 0; float v1 = p[i1];
#pragma unroll
        for (int e2 = 0; e2 < E; ++e2)
            if (e2 != i0 && e2 != ((i0 == 0) ? 1 : 0) && p[e2] > v1) { v1 = p[e2]; i1 = e2; }
        sel[t]  = i0 | (i1 << 8);
        wsel[t] = make_float2(v0 * inv, v1 * inv);
    }
}

// ---------------- Scatter: block-aggregated buckets (256 global atomics) -------
__global__ __launch_bounds__(256) void scatter_tokens(
    const int* __restrict__ sel, const float2* __restrict__ wsel,
    int* __restrict__ cnt, int* __restrict__ tok_id, float* __restrict__ tok_w)
{
    __shared__ int lh[E];
    __shared__ int gbase[E];
    int tid = threadIdx.x;
    int t = blockIdx.x * 256 + tid;
    if (tid < E) lh[tid] = 0;
    __syncthreads();
    int s = sel[t];
    float2 w = wsel[t];
    int e0 = s & 255, e1 = s >> 8;
    int p0 = atomicAdd(&lh[e0], 1);
    int p1 = atomicAdd(&lh[e1], 1);
    __syncthreads();
    if (tid < E) gbase[tid] = atomicAdd(&cnt[tid], lh[tid]);
    __syncthreads();
    int o0 = gbase[e0] + p0;
    int o1 = gbase[e1] + p1;
    tok_id[e0 * NTOK + o0] = t;
    tok_w [e0 * NTOK + o0] = w.x;
    tok_id[e1 * NTOK + o1] = t;
    tok_w [e1 * NTOK + o1] = w.y;
}

// ---------------- Old router (fallback path, no xbf) ---------------------------
__global__ __launch_bounds__(256) void router_kernel(
    const float* __restrict__ x, const float* __restrict__ ts,
    const float* __restrict__ gw, const float* __restrict__ gb,
    int* __restrict__ cnt, int* __restrict__ tok_id, float* __restrict__ tok_w)
{
    int t = blockIdx.x * blockDim.x + threadIdx.x;
    if (t >= NTOK) return;
    float acc[E];
#pragma unroll
    for (int e = 0; e < E; ++e) acc[e] = gb[e];
    const float* xr = x + (size_t)t * D;
    const float* tr = ts + (size_t)t * D;
#pragma unroll 4
    for (int d = 0; d < D; ++d) {
        float xv = xr[d] + tr[d];
        const float4* g4 = reinterpret_cast<const float4*>(gw + d * E);
        float4 a = g4[0], b = g4[1];
        acc[0] += xv * a.x; acc[1] += xv * a.y; acc[2] += xv * a.z; acc[3] += xv * a.w;
        acc[4] += xv * b.x; acc[5] += xv * b.y; acc[6] += xv * b.z; acc[7] += xv * b.w;
    }
    float m = acc[0];
#pragma unroll
    for (int e = 1; e < E; ++e) m = fmaxf(m, acc[e]);
    float p[E]; float s = 0.f;
#pragma unroll
    for (int e = 0; e < E; ++e) { p[e] = expf(acc[e] - m); s += p[e]; }
    float inv = 1.f / s;
    int i0 = 0; float v0 = p[0];
#pragma unroll
    for (int e = 1; e < E; ++e) if (p[e] > v0) { v0 = p[e]; i0 = e; }
    int i1 = (i0 == 0) ? 1 : 0; float v1 = p[i1];
#pragma unroll
    for (int e = 0; e < E; ++e) if (e != i0 && e != ((i0 == 0) ? 1 : 0) && p[e] > v1) { v1 = p[e]; i1 = e; }
    int pos0 = atomicAdd(&cnt[i0], 1);
    tok_id[i0 * NTOK + pos0] = t;
    tok_w[i0 * NTOK + pos0] = v0 * inv;
    int pos1 = atomicAdd(&cnt[i1], 1);
    tok_id[i1 * NTOK + pos1] = t;
    tok_w[i1 * NTOK + pos1] = v1 * inv;
}

// ---------------- padded gather + inverse index --------------------------------
__global__ __launch_bounds__(256) void pad_fill(
    const int* __restrict__ cnt, const int* __restrict__ sel,
    const int* __restrict__ tok_id, const float* __restrict__ tok_w,
    int* __restrict__ pad_tok, float* __restrict__ pad_w, int* __restrict__ inv)
{
    int e = blockIdx.y;
    int i = blockIdx.x * 256 + threadIdx.x;
    int s, P;
    seg_of(cnt, e, s, P);
    if (i < P) {
        int n = cnt[e];
        int tok = (i < n) ? tok_id[e * NTOK + i] : 0;
        pad_tok[s + i] = tok;
        pad_w[s + i]   = (i < n) ? tok_w[e * NTOK + i] : 0.f;
        if (i < n) {
            int k = ((sel[tok] & 255) == e) ? 0 : 1;
            inv[tok * 2 + k] = s + i;
        }
    }
}

// ---------------- Prep: both weight transposes in ONE launch -------------------
__global__ __launch_bounds__(256) void transpose_cvt2(
    const float* __restrict__ w1, short* __restrict__ w1t,
    const float* __restrict__ w2, short* __restrict__ w2t)
{
    int z = blockIdx.z;
    const float* src; short* dst; int R, C, rt, ct;
    if (z < E) {
        src = w1 + (size_t)z * D * H; dst = w1t + (size_t)z * D * H;
        R = D; C = H; rt = blockIdx.x * 64; ct = blockIdx.y * 64;
    } else {
        src = w2 + (size_t)(z - E) * H * D; dst = w2t + (size_t)(z - E) * H * D;
        R = H; C = D; rt = blockIdx.y * 64; ct = blockIdx.x * 64;
    }
    __shared__ float tsb[64][68];
    int tid = threadIdx.x;
    int r  = tid >> 4;
    int c4 = (tid & 15) * 4;
    for (int rr = r; rr < 64; rr += 16) {
        float4 v = *reinterpret_cast<const float4*>(src + (size_t)(rt + rr) * C + ct + c4);
        tsb[rr][c4] = v.x; tsb[rr][c4 + 1] = v.y; tsb[rr][c4 + 2] = v.z; tsb[rr][c4 + 3] = v.w;
    }
    __syncthreads();
    for (int cr = r; cr < 64; cr += 16) {
        short4 o;
        o.x = f2b(tsb[c4 + 0][cr]);
        o.y = f2b(tsb[c4 + 1][cr]);
        o.z = f2b(tsb[c4 + 2][cr]);
        o.w = f2b(tsb[c4 + 3][cr]);
        *reinterpret_cast<short4*>(dst + (size_t)(ct + cr) * R + rt + c4) = o;
    }
}

// ================= GEMM1: h = gelu(Xg @ W1 + b1) ==============================
// 128x128 tile, BK=32, 4 waves (2x2), 32KB LDS -> up to 5 blocks/CU.
// [slot][row] LDS layout (2-way bank alias = free), joint-prefetch vmcnt(4),
// slab coalesced epilogue.
__global__ __launch_bounds__(256, 4) void gemm1(
    const short* __restrict__ xbf,
    const short* __restrict__ w1t, const float* __restrict__ b1,
    const int* __restrict__ cnt, const int* __restrict__ pad_tok,
    short* __restrict__ hbuf)
{
    int bid = blockIdx.x;
    int e  = bid & 7;          // expert -> XCD affinity
    int u  = bid >> 3;
    int nt = u & 15;           // nt fastest: same-A blocks adjacent
    int mt = u >> 4;           // 0..63
    int s0, P;
    seg_of(cnt, e, s0, P);
    if (mt * 128 >= P) return;
    int p0 = s0 + mt * 128;    // P is 128-aligned -> tile always full

    // 32 KB: As[2] @0 (4096 shorts each), Bs[2] @8192; whole array = epilogue slab
    __shared__ short lds[16384];

    int tid = threadIdx.x;
    int wv = tid >> 6, lane = tid & 63;
    int q = lane >> 4, r = lane & 15;
    int wm = wv >> 1, wn = wv & 1;      // 2 x 2 wave grid, 64x64 per wave

    const short* w1e = w1t + (size_t)e * H * D;

    // staging: 512 chunks of 16B per matrix; chunk g: slot = g>>7, row = g&127
    const short* asrc[2];
    const short* bsrc[2];
#pragma unroll
    for (int p = 0; p < 2; ++p) {
        int g = p * 256 + tid;
        int slot = g >> 7, row = g & 127;
        int tok = pad_tok[p0 + row];
        asrc[p] = xbf + (size_t)tok * D + slot * 8;
        bsrc[p] = w1e + (size_t)(nt * 128 + row) * D + slot * 8;
    }

    f32x4 acc[4][4];
#pragma unroll
    for (int m = 0; m < 4; ++m)
#pragma unroll
        for (int n = 0; n < 4; ++n) acc[m][n] = (f32x4){0.f, 0.f, 0.f, 0.f};

    // prologue: stage t=0 into buf 0
#pragma unroll
    for (int p = 0; p < 2; ++p) {
        gll16(asrc[p], &lds[p * 2048 + wv * 512]);
        gll16(bsrc[p], &lds[8192 + p * 2048 + wv * 512]);
    }

    const int NTT = D / 32;   // 16
    for (int t = 0; t < NTT; ++t) {
        int b = t & 1;
        if (t + 1 < NTT) {
            int kk = (t + 1) * 32;
#pragma unroll
            for (int p = 0; p < 2; ++p) {
                gll16(asrc[p] + kk, &lds[(b ^ 1) * 4096 + p * 2048 + wv * 512]);
                gll16(bsrc[p] + kk, &lds[8192 + (b ^ 1) * 4096 + p * 2048 + wv * 512]);
            }
            asm volatile("s_waitcnt vmcnt(4)" ::: "memory");
        } else {
            asm volatile("s_waitcnt vmcnt(0)" ::: "memory");
        }
        __builtin_amdgcn_s_barrier();
        __builtin_amdgcn_sched_barrier(0);

        const short* Ab = &lds[b * 4096];
        const short* Bb = &lds[8192 + b * 4096];
        bf16x8 a[4], bb[4];
#pragma unroll
        for (int m = 0; m < 4; ++m)
            a[m] = *reinterpret_cast<const bf16x8*>(Ab + q * 1024 + (wm * 64 + m * 16 + r) * 8);
#pragma unroll
        for (int n = 0; n < 4; ++n)
            bb[n] = *reinterpret_cast<const bf16x8*>(Bb + q * 1024 + (wn * 64 + n * 16 + r) * 8);
        __builtin_amdgcn_s_setprio(1);
#pragma unroll
        for (int m = 0; m < 4; ++m)
#pragma unroll
            for (int n = 0; n < 4; ++n)
                acc[m][n] = __builtin_amdgcn_mfma_f32_16x16x32_bf16(a[m], bb[n], acc[m][n], 0, 0, 0);
        __builtin_amdgcn_s_setprio(0);
        if (t + 1 < NTT) {
            __builtin_amdgcn_s_barrier();
            __builtin_amdgcn_sched_barrier(0);
        }
    }
    __syncthreads();   // all LDS reads done -> reuse lds as 128x128 slab (32 KB)

    // -------- epilogue: gelu+bias -> slab -> coalesced 16B stores --------------
    const float* b1e = b1 + (size_t)e * H;
    float bv[4];
#pragma unroll
    for (int n = 0; n < 4; ++n) bv[n] = b1e[nt * 128 + wn * 64 + n * 16 + r];
#pragma unroll
    for (int m = 0; m < 4; ++m)
#pragma unroll
        for (int j = 0; j < 4; ++j) {
            int lr = wm * 64 + m * 16 + q * 4 + j;
#pragma unroll
            for (int n = 0; n < 4; ++n) {
                int col = wn * 64 + n * 16 + r;
                lds[lr * 128 + col] = f2b(gelu_fast(acc[m][n][j] + bv[n]));
            }
        }
    __syncthreads();
#pragma unroll
    for (int p = 0; p < 8; ++p) {
        int idx = p * 256 + tid;       // 0..2047 = 128 rows x 16 chunks
        int row = idx >> 4;
        int c16 = idx & 15;
        bf16x8 v = *reinterpret_cast<const bf16x8*>(&lds[row * 128 + c16 * 8]);
        *reinterpret_cast<bf16x8*>(&hbuf[(size_t)(p0 + row) * H + nt * 128 + c16 * 8]) = v;
    }
}

// ================= GEMM2: y = h @ W2 + b2 ======================================
// 64x128 tile, BK=32, 4 waves (2x2), 24KB LDS -> 1040 working blocks ~4/CU.
__global__ __launch_bounds__(256, 4) void gemm2(
    const short* __restrict__ hbuf,
    const short* __restrict__ w2t, const float* __restrict__ b2,
    const int* __restrict__ cnt,
    short* __restrict__ ybuf)
{
    int bid = blockIdx.x;
    int e  = bid & 7;
    int u  = bid >> 3;
    int nt = u & 3;            // nt fastest: same-A blocks adjacent
    int mt = u >> 2;           // 0..127 (64-row tiles)
    int s0, P;
    seg_of(cnt, e, s0, P);
    if (mt * 64 >= P) return;
    int p0 = s0 + mt * 64;     // P 128-aligned -> 64-tiles always full

    // 24 KB: As[2] @0 (2048 shorts each), Bs[2] @4096 (4096 each);
    // lds[0..8191] = 64x128 epilogue slab
    __shared__ short lds[12288];

    int tid = threadIdx.x;
    int wv = tid >> 6, lane = tid & 63;
    int q = lane >> 4, r = lane & 15;
    int wm = wv >> 1, wn = wv & 1;      // rows: wm*32 (m=0..1); cols: wn*64 (n=0..3)

    const short* w2e = w2t + (size_t)e * D * H;

    // A: 256 chunks (slot=g>>6, row=g&63), 1/thread. B: 512 chunks, 2/thread.
    const short* asrc;
    {
        int slot = tid >> 6, row = tid & 63;
        asrc = hbuf + (size_t)(p0 + row) * H + slot * 8;
    }
    const short* bsrc[2];
#pragma unroll
    for (int p = 0; p < 2; ++p) {
        int g = p * 256 + tid;
        int slot = g >> 7, row = g & 127;
        bsrc[p] = w2e + (size_t)(nt * 128 + row) * H + slot * 8;
    }

    f32x4 acc[2][4];
#pragma unroll
    for (int m = 0; m < 2; ++m)
#pragma unroll
        for (int n = 0; n < 4; ++n) acc[m][n] = (f32x4){0.f, 0.f, 0.f, 0.f};

    // prologue: stage t=0 into buf 0
    gll16(asrc, &lds[wv * 512]);
#pragma unroll
    for (int p = 0; p < 2; ++p)
        gll16(bsrc[p], &lds[4096 + p * 2048 + wv * 512]);

    const int NTT = H / 32;   // 64
    for (int t = 0; t < NTT; ++t) {
        int b = t & 1;
        if (t + 1 < NTT) {
            int kk = (t + 1) * 32;
            gll16(asrc + kk, &lds[(b ^ 1) * 2048 + wv * 512]);
#pragma unroll
            for (int p = 0; p < 2; ++p)
                gll16(bsrc[p] + kk, &lds[4096 + (b ^ 1) * 4096 + p * 2048 + wv * 512]);
            asm volatile("s_waitcnt vmcnt(3)" ::: "memory");
        } else {
            asm volatile("s_waitcnt vmcnt(0)" ::: "memory");
        }
        __builtin_amdgcn_s_barrier();
        __builtin_amdgcn_sched_barrier(0);

        const short* Ab = &lds[b * 2048];
        const short* Bb = &lds[4096 + b * 4096];
        bf16x8 a[2], bb[4];
#pragma unroll
        for (int m = 0; m < 2; ++m)
            a[m] = *reinterpret_cast<const bf16x8*>(Ab + q * 512 + (wm * 32 + m * 16 + r) * 8);
#pragma unroll
        for (int n = 0; n < 4; ++n)
            bb[n] = *reinterpret_cast<const bf16x8*>(Bb + q * 1024 + (wn * 64 + n * 16 + r) * 8);
        __builtin_amdgcn_s_setprio(1);
#pragma unroll
        for (int m = 0; m < 2; ++m)
#pragma unroll
            for (int n = 0; n < 4; ++n)
                acc[m][n] = __builtin_amdgcn_mfma_f32_16x16x32_bf16(a[m], bb[n], acc[m][n], 0, 0, 0);
        __builtin_amdgcn_s_setprio(0);
        if (t + 1 < NTT) {
            __builtin_amdgcn_s_barrier();
            __builtin_amdgcn_sched_barrier(0);
        }
    }
    __syncthreads();

    // -------- epilogue: bias -> 64x128 slab -> coalesced 16B stores ------------
    const float* b2e = b2 + (size_t)e * D;
    float bv[4];
#pragma unroll
    for (int n = 0; n < 4; ++n) bv[n] = b2e[nt * 128 + wn * 64 + n * 16 + r];
#pragma unroll
    for (int m = 0; m < 2; ++m)
#pragma unroll
        for (int j = 0; j < 4; ++j) {
            int lr = wm * 32 + m * 16 + q * 4 + j;
#pragma unroll
            for (int n = 0; n < 4; ++n) {
                int col = wn * 64 + n * 16 + r;
                lds[lr * 128 + col] = f2b(acc[m][n][j] + bv[n]);
            }
        }
    __syncthreads();
#pragma unroll
    for (int p = 0; p < 4; ++p) {
        int idx = p * 256 + tid;       // 0..1023 = 64 rows x 16 chunks
        int row = idx >> 4;
        int c16 = idx & 15;
        bf16x8 v = *reinterpret_cast<const bf16x8*>(&lds[row * 128 + c16 * 8]);
        *reinterpret_cast<bf16x8*>(&ybuf[(size_t)(p0 + row) * D + nt * 128 + c16 * 8]) = v;
    }
}

// ================= Combine: out[t] = w0*y[p0] + w1*y[p1] ======================
__global__ __launch_bounds__(256) void combine(
    const short* __restrict__ ybuf, const int* __restrict__ inv,
    const float2* __restrict__ wsel, float* __restrict__ out)
{
    int gid = blockIdx.x * 256 + threadIdx.x;
    int t  = gid >> 7;          // token
    int c4 = (gid & 127) * 4;   // col group
    float2 w = wsel[t];
    int i0 = inv[t * 2], i1 = inv[t * 2 + 1];
    short4 y0 = *reinterpret_cast<const short4*>(ybuf + (size_t)i0 * D + c4);
    short4 y1 = *reinterpret_cast<const short4*>(ybuf + (size_t)i1 * D + c4);
    float4 o;
    o.x = w.x * b2f(y0.x) + w.y * b2f(y1.x);
    o.y = w.x * b2f(y0.y) + w.y * b2f(y1.y);
    o.z = w.x * b2f(y0.z) + w.y * b2f(y1.z);
    o.w = w.x * b2f(y0.w) + w.y * b2f(y1.w);
    *reinterpret_cast<float4*>(out + (size_t)t * D + c4) = o;
}

// ---------------- Round-2 fused MFMA FFN (fallback if ws too small) ------------
#define TMM 64
#define FCC 64
#define XPAD 520
#define HPD 72

__global__ __launch_bounds__(512, 2) void ffn_mfma(
    const float* __restrict__ x,
    const short* __restrict__ w1t, const float* __restrict__ b1,
    const short* __restrict__ w2t, const float* __restrict__ b2,
    const int* __restrict__ cnt, const int* __restrict__ tok_id,
    const float* __restrict__ tok_w,
    float* __restrict__ out)
{
    int b = blockIdx.x;
    int e = b & 7;
    int tile = b >> 3;
    int n = cnt[e];
    int start = tile * TMM;
    if (start >= n) return;
    int nvalid = min(TMM, n - start);

    __shared__ short xs[TMM * XPAD];
    __shared__ short hs[TMM * HPD];
    __shared__ int   stok[TMM];
    __shared__ float sw[TMM];

    int tid = threadIdx.x;
    if (tid < TMM) {
        int tok = 0; float w = 0.f;
        if (tid < nvalid) {
            tok = tok_id[e * NTOK + start + tid];
            w   = tok_w[e * NTOK + start + tid];
        }
        stok[tid] = tok; sw[tid] = w;
    }
    __syncthreads();

    for (int idx = tid; idx < TMM * (D / 4); idx += 512) {
        int row = idx >> 7;
        int c4  = (idx & 127) << 2;
        float4 v = *reinterpret_cast<const float4*>(x + (size_t)stok[row] * D + c4);
        short4 o; o.x = f2b(v.x); o.y = f2b(v.y); o.z = f2b(v.z); o.w = f2b(v.w);
        *reinterpret_cast<short4*>(&xs[row * XPAD + c4]) = o;
    }
    __syncthreads();

    const int lane = tid & 63, wave = tid >> 6;
    const int wm = wave >> 2, wn = wave & 3;
    const int q = lane >> 4,  r = lane & 15;

    const short* w1e = w1t + (size_t)e * H * D;
    const short* w2e = w2t + (size_t)e * D * H;
    const float* b1e = b1 + (size_t)e * H;
    const float* b2e = b2 + (size_t)e * D;

    f32x4 acc[2][8];
#pragma unroll
    for (int i = 0; i < 2; ++i)
#pragma unroll
        for (int j = 0; j < 8; ++j) acc[i][j] = (f32x4){0.f, 0.f, 0.f, 0.f};

    for (int fc = 0; fc < H; fc += FCC) {
        int f = fc + wn * 16 + r;
        float b1f = b1e[f];
        f32x4 h0 = {b1f, b1f, b1f, b1f};
        f32x4 h1 = h0;
        const short* wrow = w1e + (size_t)f * D;
        const short* a0p = &xs[(wm * 32 + r) * XPAD + q * 8];
        const short* a1p = a0p + 16 * XPAD;
#pragma unroll
        for (int ks = 0; ks < 16; ++ks) {
            bf16x8 bfr = *reinterpret_cast<const bf16x8*>(wrow + ks * 32 + q * 8);
            bf16x8 a0  = *reinterpret_cast<const bf16x8*>(a0p + ks * 32);
            bf16x8 a1  = *reinterpret_cast<const bf16x8*>(a1p + ks * 32);
            h0 = __builtin_amdgcn_mfma_f32_16x16x32_bf16(a0, bfr, h0, 0, 0, 0);
            h1 = __builtin_amdgcn_mfma_f32_16x16x32_bf16(a1, bfr, h1, 0, 0, 0);
        }
        {
            int c = wn * 16 + r;
#pragma unroll
            for (int j = 0; j < 4; ++j) {
                hs[(wm * 32 + q * 4 + j) * HPD + c]      = f2b(gelu_exact(h0[j]));
                hs[(wm * 32 + 16 + q * 4 + j) * HPD + c] = f2b(gelu_exact(h1[j]));
            }
        }
        __syncthreads();
#pragma unroll
        for (int ks = 0; ks < 2; ++ks) {
            bf16x8 a20 = *reinterpret_cast<const bf16x8*>(&hs[(wm * 32 + r) * HPD + ks * 32 + q * 8]);
            bf16x8 a21 = *reinterpret_cast<const bf16x8*>(&hs[(wm * 32 + 16 + r) * HPD + ks * 32 + q * 8]);
#pragma unroll
            for (int nr = 0; nr < 8; ++nr) {
                int dout = wn * 128 + nr * 16 + r;
                bf16x8 bfr = *reinterpret_cast<const bf16x8*>(
                    w2e + (size_t)dout * H + fc + ks * 32 + q * 8);
                acc[0][nr] = __builtin_amdgcn_mfma_f32_16x16x32_bf16(a20, bfr, acc[0][nr], 0, 0, 0);
                acc[1][nr] = __builtin_amdgcn_mfma_f32_16x16x32_bf16(a21, bfr, acc[1][nr], 0, 0, 0);
            }
        }
        __syncthreads();
    }

#pragma unroll
    for (int mrep = 0; mrep < 2; ++mrep) {
#pragma unroll
        for (int j = 0; j < 4; ++j) {
            int rl = wm * 32 + mrep * 16 + q * 4 + j;
            if (rl < nvalid) {
                float w = sw[rl];
                if (w != 0.f) {
                    float* orow = out + (size_t)stok[rl] * D;
#pragma unroll
                    for (int nr = 0; nr < 8; ++nr) {
                        int dout = wn * 128 + nr * 16 + r;
                        f32x4 a = acc[mrep][nr];
                        atomicAdd(&orow[dout], w * (a[j] + b2e[dout]));
                    }
                }
            }
        }
    }
}

extern "C" void kernel_launch(void* const* d_in, const int* in_sizes, int n_in,
                              void* d_out, int out_size, void* d_ws, size_t ws_size,
                              hipStream_t stream) {
    const float* x  = (const float*)d_in[0];
    const float* ts = (const float*)d_in[1];
    const float* gw = (const float*)d_in[2];
    const float* gb = (const float*)d_in[3];
    const float* w1 = (const float*)d_in[4];
    const float* b1 = (const float*)d_in[5];
    const float* w2 = (const float*)d_in[6];
    const float* b2 = (const float*)d_in[7];
    float* out = (float*)d_out;

    // ws layout (bytes):
    // cnt@0 | tok_id@1024 (256K) | tok_w@263168 (256K) |
    // pad_tok@525312 (68K) | pad_w@594944 (68K) | sel@665600 (32K) |
    // wsel@700416 (64K) | inv@765952 (64K) | xbf@1M (8M) |
    // w1t@9437184 (16.78M) | w2t@26214400 (16.78M) | hbuf@42991616 (71.3M)
    // ybuf@1M (17.83M) overlays xbf+w1t — both dead after gemm1.
    int*    cnt     = (int*)d_ws;
    int*    tok_id  = (int*)((char*)d_ws + 1024);
    float*  tok_w   = (float*)((char*)d_ws + 263168);
    int*    pad_tok = (int*)((char*)d_ws + 525312);
    float*  pad_w   = (float*)((char*)d_ws + 594944);
    int*    sel     = (int*)((char*)d_ws + 665600);
    float2* wsel    = (float2*)((char*)d_ws + 700416);
    int*    inv     = (int*)((char*)d_ws + 765952);
    short*  xbf     = (short*)((char*)d_ws + 1048576);
    short*  w1t     = (short*)((char*)d_ws + 9437184);
    short*  w2t     = (short*)((char*)d_ws + 26214400);
    short*  hbuf    = (short*)((char*)d_ws + 42991616);
    short*  ybuf    = (short*)((char*)d_ws + 1048576);   // overlays xbf+w1t
    const size_t ws_need = 114294784;

    hipMemsetAsync(cnt, 0, 64, stream);

    if (ws_size >= ws_need) {
        router_score<<<NTOK / 4, 256, 0, stream>>>(x, ts, gw, gb, sel, wsel, xbf);
        scatter_tokens<<<NTOK / 256, 256, 0, stream>>>(sel, wsel, cnt, tok_id, tok_w);
        pad_fill<<<dim3(NTOK / 256, E), 256, 0, stream>>>(cnt, sel, tok_id, tok_w,
                                                          pad_tok, pad_w, inv);
        transpose_cvt2<<<dim3(8, 32, 2 * E), 256, 0, stream>>>(w1, w1t, w2, w2t);
        gemm1<<<E * 16 * 64, 256, 0, stream>>>(xbf, w1t, b1, cnt, pad_tok, hbuf);
        gemm2<<<E * 4 * 128, 256, 0, stream>>>(hbuf, w2t, b2, cnt, ybuf);
        combine<<<NTOK * (D / 4) / 256, 256, 0, stream>>>(ybuf, inv, wsel, out);
    } else {
        // fallback: round-2 layout (w1t@1M, w2t after)
        hipMemsetAsync(out, 0, (size_t)out_size * sizeof(float), stream);
        short* w1t_f = (short*)((char*)d_ws + (1u << 20));
        short* w2t_f = w1t_f + (size_t)E * D * H;
        router_kernel<<<NTOK / 256, 256, 0, stream>>>(x, ts, gw, gb, cnt, tok_id, tok_w);
        transpose_cvt2<<<dim3(8, 32, 2 * E), 256, 0, stream>>>(w1, w1t_f, w2, w2t_f);
        ffn_mfma<<<(NTOK / TMM) * E, 512, 0, stream>>>(
            x, w1t_f, b1, w2t_f, b2, cnt, tok_id, tok_w, out);
    }
}

// Round 15
// 190.254 us; speedup vs baseline: 1.3722x; 1.3722x over previous
//
#include <hip/hip_runtime.h>
#include <math.h>

#define D 512
#define H 2048
#define E 8
#define NTOK 8192
#define BK 64
#define PTMAX 17408   // capacity of pad_tok/pad_w arrays (rows)

typedef __attribute__((ext_vector_type(8))) short bf16x8;
typedef __attribute__((ext_vector_type(4))) float f32x4;

__device__ __forceinline__ short f2b(float v) {
    unsigned u = __float_as_uint(v);
    unsigned r = (u + 0x7FFFu + ((u >> 16) & 1u)) >> 16;  // RNE
    return (short)r;
}
__device__ __forceinline__ float b2f(short v) {
    unsigned u = ((unsigned)(unsigned short)v) << 16;
    return __uint_as_float(u);
}
__device__ __forceinline__ float gelu_exact(float v) {
    return 0.5f * v * (1.0f + erff(v * 0.70710678118654752f));
}
// tanh-form gelu via HW exp: max |err| ~1e-3 << bf16-h quantization.
__device__ __forceinline__ float gelu_fast(float v) {
    float u2 = -1.5957691216f * (v + 0.044715f * v * v * v);
    return v / (1.f + __expf(u2));
}
// async global->LDS, 16B per lane; LDS dest is wave-uniform base + lane*16
__device__ __forceinline__ void gll16(const void* g, void* l) {
    __builtin_amdgcn_global_load_lds(
        (const __attribute__((address_space(1))) void*)g,
        (__attribute__((address_space(3))) void*)l, 16, 0, 0);
}
// padded (128-aligned) prefix over cnt[]
__device__ __forceinline__ void seg_of(const int* cnt, int e, int& s0, int& P) {
    int o = 0;
#pragma unroll
    for (int i = 0; i < E; ++i) {
        int p = (cnt[i] + 127) & ~127;
        if (i < e) o += p;
        if (i == e) P = p;
    }
    s0 = o;
}

// ---------------- Router score: wave-per-token, NO global atomics --------------
__global__ __launch_bounds__(256) void router_score(
    const float* __restrict__ x, const float* __restrict__ ts,
    const float* __restrict__ gw, const float* __restrict__ gb,
    int* __restrict__ sel, float2* __restrict__ wsel,
    short* __restrict__ xbf)
{
    int wave = threadIdx.x >> 6, lane = threadIdx.x & 63;
    int t = blockIdx.x * 4 + wave;

    const float* xr = x + (size_t)t * D + lane * 8;
    const float* tr = ts + (size_t)t * D + lane * 8;
    float4 xa = *reinterpret_cast<const float4*>(xr);
    float4 xb = *reinterpret_cast<const float4*>(xr + 4);
    float4 ta = *reinterpret_cast<const float4*>(tr);
    float4 tb = *reinterpret_cast<const float4*>(tr + 4);

    bf16x8 o;
    o[0] = f2b(xa.x); o[1] = f2b(xa.y); o[2] = f2b(xa.z); o[3] = f2b(xa.w);
    o[4] = f2b(xb.x); o[5] = f2b(xb.y); o[6] = f2b(xb.z); o[7] = f2b(xb.w);
    *reinterpret_cast<bf16x8*>(xbf + (size_t)t * D + lane * 8) = o;

    float v[8] = {xa.x + ta.x, xa.y + ta.y, xa.z + ta.z, xa.w + ta.w,
                  xb.x + tb.x, xb.y + tb.y, xb.z + tb.z, xb.w + tb.w};
    float acc[E];
#pragma unroll
    for (int e2 = 0; e2 < E; ++e2) acc[e2] = 0.f;
#pragma unroll
    for (int i = 0; i < 8; ++i) {
        const float4* gr = reinterpret_cast<const float4*>(gw + (size_t)(lane * 8 + i) * E);
        float4 g0 = gr[0], g1 = gr[1];
        acc[0] += v[i] * g0.x; acc[1] += v[i] * g0.y; acc[2] += v[i] * g0.z; acc[3] += v[i] * g0.w;
        acc[4] += v[i] * g1.x; acc[5] += v[i] * g1.y; acc[6] += v[i] * g1.z; acc[7] += v[i] * g1.w;
    }
#pragma unroll
    for (int m = 32; m; m >>= 1) {
#pragma unroll
        for (int e2 = 0; e2 < E; ++e2) acc[e2] += __shfl_xor(acc[e2], m);
    }
    if (lane == 0) {
        float p[E]; float mx;
#pragma unroll
        for (int e2 = 0; e2 < E; ++e2) p[e2] = acc[e2] + gb[e2];
        mx = p[0];
#pragma unroll
        for (int e2 = 1; e2 < E; ++e2) mx = fmaxf(mx, p[e2]);
        float s = 0.f;
#pragma unroll
        for (int e2 = 0; e2 < E; ++e2) { p[e2] = expf(p[e2] - mx); s += p[e2]; }
        float inv = 1.f / s;
        int i0 = 0; float v0 = p[0];
#pragma unroll
        for (int e2 = 1; e2 < E; ++e2) if (p[e2] > v0) { v0 = p[e2]; i0 = e2; }
        int i1 = (i0 == 0) ? 1 : 0; float v1 = p[i1];
#pragma unroll
        for (int e2 = 0; e2 < E; ++e2)
            if (e2 != i0 && e2 != ((i0 == 0) ? 1 : 0) && p[e2] > v1) { v1 = p[e2]; i1 = e2; }
        sel[t]  = i0 | (i1 << 8);
        wsel[t] = make_float2(v0 * inv, v1 * inv);
    }
}

// ---------------- Scatter: block-aggregated buckets (256 global atomics) -------
__global__ __launch_bounds__(256) void scatter_tokens(
    const int* __restrict__ sel, const float2* __restrict__ wsel,
    int* __restrict__ cnt, int* __restrict__ tok_id, float* __restrict__ tok_w)
{
    __shared__ int lh[E];
    __shared__ int gbase[E];
    int tid = threadIdx.x;
    int t = blockIdx.x * 256 + tid;
    if (tid < E) lh[tid] = 0;
    __syncthreads();
    int s = sel[t];
    float2 w = wsel[t];
    int e0 = s & 255, e1 = s >> 8;
    int p0 = atomicAdd(&lh[e0], 1);
    int p1 = atomicAdd(&lh[e1], 1);
    __syncthreads();
    if (tid < E) gbase[tid] = atomicAdd(&cnt[tid], lh[tid]);
    __syncthreads();
    int o0 = gbase[e0] + p0;
    int o1 = gbase[e1] + p1;
    tok_id[e0 * NTOK + o0] = t;
    tok_w [e0 * NTOK + o0] = w.x;
    tok_id[e1 * NTOK + o1] = t;
    tok_w [e1 * NTOK + o1] = w.y;
}

// ---------------- Old router (fallback path, no xbf) ---------------------------
__global__ __launch_bounds__(256) void router_kernel(
    const float* __restrict__ x, const float* __restrict__ ts,
    const float* __restrict__ gw, const float* __restrict__ gb,
    int* __restrict__ cnt, int* __restrict__ tok_id, float* __restrict__ tok_w)
{
    int t = blockIdx.x * blockDim.x + threadIdx.x;
    if (t >= NTOK) return;
    float acc[E];
#pragma unroll
    for (int e = 0; e < E; ++e) acc[e] = gb[e];
    const float* xr = x + (size_t)t * D;
    const float* tr = ts + (size_t)t * D;
#pragma unroll 4
    for (int d = 0; d < D; ++d) {
        float xv = xr[d] + tr[d];
        const float4* g4 = reinterpret_cast<const float4*>(gw + d * E);
        float4 a = g4[0], b = g4[1];
        acc[0] += xv * a.x; acc[1] += xv * a.y; acc[2] += xv * a.z; acc[3] += xv * a.w;
        acc[4] += xv * b.x; acc[5] += xv * b.y; acc[6] += xv * b.z; acc[7] += xv * b.w;
    }
    float m = acc[0];
#pragma unroll
    for (int e = 1; e < E; ++e) m = fmaxf(m, acc[e]);
    float p[E]; float s = 0.f;
#pragma unroll
    for (int e = 0; e < E; ++e) { p[e] = expf(acc[e] - m); s += p[e]; }
    float inv = 1.f / s;
    int i0 = 0; float v0 = p[0];
#pragma unroll
    for (int e = 1; e < E; ++e) if (p[e] > v0) { v0 = p[e]; i0 = e; }
    int i1 = (i0 == 0) ? 1 : 0; float v1 = p[i1];
#pragma unroll
    for (int e = 0; e < E; ++e) if (e != i0 && e != ((i0 == 0) ? 1 : 0) && p[e] > v1) { v1 = p[e]; i1 = e; }
    int pos0 = atomicAdd(&cnt[i0], 1);
    tok_id[i0 * NTOK + pos0] = t;
    tok_w[i0 * NTOK + pos0] = v0 * inv;
    int pos1 = atomicAdd(&cnt[i1], 1);
    tok_id[i1 * NTOK + pos1] = t;
    tok_w[i1 * NTOK + pos1] = v1 * inv;
}

// ---------------- padded gather + inverse index --------------------------------
__global__ __launch_bounds__(256) void pad_fill(
    const int* __restrict__ cnt, const int* __restrict__ sel,
    const int* __restrict__ tok_id, const float* __restrict__ tok_w,
    int* __restrict__ pad_tok, float* __restrict__ pad_w, int* __restrict__ inv)
{
    int e = blockIdx.y;
    int i = blockIdx.x * 256 + threadIdx.x;
    int s, P;
    seg_of(cnt, e, s, P);
    if (i < P) {
        int n = cnt[e];
        int tok = (i < n) ? tok_id[e * NTOK + i] : 0;
        pad_tok[s + i] = tok;
        pad_w[s + i]   = (i < n) ? tok_w[e * NTOK + i] : 0.f;
        if (i < n) {
            int k = ((sel[tok] & 255) == e) ? 0 : 1;
            inv[tok * 2 + k] = s + i;
        }
    }
}

// ---------------- Prep: both weight transposes in ONE launch -------------------
__global__ __launch_bounds__(256) void transpose_cvt2(
    const float* __restrict__ w1, short* __restrict__ w1t,
    const float* __restrict__ w2, short* __restrict__ w2t)
{
    int z = blockIdx.z;
    const float* src; short* dst; int R, C, rt, ct;
    if (z < E) {
        src = w1 + (size_t)z * D * H; dst = w1t + (size_t)z * D * H;
        R = D; C = H; rt = blockIdx.x * 64; ct = blockIdx.y * 64;
    } else {
        src = w2 + (size_t)(z - E) * H * D; dst = w2t + (size_t)(z - E) * H * D;
        R = H; C = D; rt = blockIdx.y * 64; ct = blockIdx.x * 64;
    }
    __shared__ float tsb[64][68];
    int tid = threadIdx.x;
    int r  = tid >> 4;
    int c4 = (tid & 15) * 4;
    for (int rr = r; rr < 64; rr += 16) {
        float4 v = *reinterpret_cast<const float4*>(src + (size_t)(rt + rr) * C + ct + c4);
        tsb[rr][c4] = v.x; tsb[rr][c4 + 1] = v.y; tsb[rr][c4 + 2] = v.z; tsb[rr][c4 + 3] = v.w;
    }
    __syncthreads();
    for (int cr = r; cr < 64; cr += 16) {
        short4 o;
        o.x = f2b(tsb[c4 + 0][cr]);
        o.y = f2b(tsb[c4 + 1][cr]);
        o.z = f2b(tsb[c4 + 2][cr]);
        o.w = f2b(tsb[c4 + 3][cr]);
        *reinterpret_cast<short4*>(dst + (size_t)(ct + cr) * R + rt + c4) = o;
    }
}

// ================= GEMM1: h = gelu(Xg @ W1 + b1) ==============================
// r13 configuration (measured best): 128x128 tile, BK=64, 4 waves (2x2),
// 64KB LDS -> 2 blocks/CU, joint-prefetch counted vmcnt(8), T2 slot-swizzle,
// slab coalesced epilogue, nt-fastest ordering, cached stores.
__global__ __launch_bounds__(256, 2) void gemm1(
    const short* __restrict__ xbf,
    const short* __restrict__ w1t, const float* __restrict__ b1,
    const int* __restrict__ cnt, const int* __restrict__ pad_tok,
    short* __restrict__ hbuf)
{
    int bid = blockIdx.x;
    int e  = bid & 7;          // expert -> XCD affinity
    int u  = bid >> 3;
    int nt = u & 15;           // nt fastest: same-A blocks adjacent
    int mt = u >> 4;           // 0..63
    int s0, P;
    seg_of(cnt, e, s0, P);
    if (mt * 128 >= P) return;
    int p0 = s0 + mt * 128;    // P is 128-aligned -> tile always full

    __shared__ short As[2][128 * BK];   // 16 KB per buf; doubles as epilogue slab
    __shared__ short Bs[2][128 * BK];   // 64 KB total

    int tid = threadIdx.x;
    int wv = tid >> 6, lane = tid & 63;
    int q = lane >> 4, r = lane & 15;
    int wm = wv >> 1, wn = wv & 1;      // 2 x 2 wave grid, 64x64 per wave

    const short* w1e = w1t + (size_t)e * H * D;

    const short* asrc[4];
    const short* bsrc[4];
#pragma unroll
    for (int p = 0; p < 4; ++p) {
        int g = p * 256 + tid;
        int row = g >> 3;                      // 0..127
        int slot = (g & 7) ^ (row & 7);        // T2 swizzle on SOURCE
        int tok = pad_tok[p0 + row];
        asrc[p] = xbf + (size_t)tok * D + slot * 8;
        bsrc[p] = w1e + (size_t)(nt * 128 + row) * D + slot * 8;
    }

    f32x4 acc[4][4];
#pragma unroll
    for (int m = 0; m < 4; ++m)
#pragma unroll
        for (int n = 0; n < 4; ++n) acc[m][n] = (f32x4){0.f, 0.f, 0.f, 0.f};

    const int xorv = r & 7;

#pragma unroll
    for (int p = 0; p < 4; ++p) {
        gll16(asrc[p], &As[0][p * 2048 + wv * 512]);
        gll16(bsrc[p], &Bs[0][p * 2048 + wv * 512]);
    }

    const int NTT = D / BK;   // 8
    for (int t = 0; t < NTT; ++t) {
        int b = t & 1;
        if (t + 1 < NTT) {
            int kk = (t + 1) * BK;
#pragma unroll
            for (int p = 0; p < 4; ++p) {
                gll16(asrc[p] + kk, &As[b ^ 1][p * 2048 + wv * 512]);
                gll16(bsrc[p] + kk, &Bs[b ^ 1][p * 2048 + wv * 512]);
            }
            asm volatile("s_waitcnt vmcnt(8)" ::: "memory");
        } else {
            asm volatile("s_waitcnt vmcnt(0)" ::: "memory");
        }
        __builtin_amdgcn_s_barrier();
        __builtin_amdgcn_sched_barrier(0);

        const char* Ab = (const char*)&As[b][0];
        const char* Bb = (const char*)&Bs[b][0];
#pragma unroll
        for (int ks = 0; ks < 2; ++ks) {
            int sslot = ((ks * 4 + q) ^ xorv) << 4;
            bf16x8 a[4], bb[4];
#pragma unroll
            for (int m = 0; m < 4; ++m)
                a[m] = *(const bf16x8*)(Ab + (wm * 64 + m * 16 + r) * 128 + sslot);
#pragma unroll
            for (int n = 0; n < 4; ++n)
                bb[n] = *(const bf16x8*)(Bb + (wn * 64 + n * 16 + r) * 128 + sslot);
            __builtin_amdgcn_s_setprio(1);
#pragma unroll
            for (int m = 0; m < 4; ++m)
#pragma unroll
                for (int n = 0; n < 4; ++n)
                    acc[m][n] = __builtin_amdgcn_mfma_f32_16x16x32_bf16(a[m], bb[n], acc[m][n], 0, 0, 0);
            __builtin_amdgcn_s_setprio(0);
        }
        if (t + 1 < NTT) {
            __builtin_amdgcn_s_barrier();
            __builtin_amdgcn_sched_barrier(0);
        }
    }
    __syncthreads();   // LDS reads done -> reuse As as 128x128 slab (32 KB)

    // -------- epilogue: gelu+bias -> slab -> coalesced 16B stores (cached) -----
    const float* b1e = b1 + (size_t)e * H;
    float bv[4];
#pragma unroll
    for (int n = 0; n < 4; ++n) bv[n] = b1e[nt * 128 + wn * 64 + n * 16 + r];
    short* slab = &As[0][0];
#pragma unroll
    for (int m = 0; m < 4; ++m)
#pragma unroll
        for (int j = 0; j < 4; ++j) {
            int lr = wm * 64 + m * 16 + q * 4 + j;
#pragma unroll
            for (int n = 0; n < 4; ++n) {
                int col = wn * 64 + n * 16 + r;
                slab[lr * 128 + col] = f2b(gelu_fast(acc[m][n][j] + bv[n]));
            }
        }
    __syncthreads();
#pragma unroll
    for (int p = 0; p < 8; ++p) {
        int idx = p * 256 + tid;       // 0..2047 = 128 rows x 16 chunks
        int row = idx >> 4;
        int c16 = idx & 15;
        bf16x8 v = *reinterpret_cast<const bf16x8*>(&slab[row * 128 + c16 * 8]);
        *reinterpret_cast<bf16x8*>(&hbuf[(size_t)(p0 + row) * H + nt * 128 + c16 * 8]) = v;
    }
}

// ================= GEMM2: y = h @ W2 + b2 (no atomics, cached A) ===============
__global__ __launch_bounds__(256, 2) void gemm2(
    const short* __restrict__ hbuf,
    const short* __restrict__ w2t, const float* __restrict__ b2,
    const int* __restrict__ cnt,
    short* __restrict__ ybuf)
{
    int bid = blockIdx.x;
    int e  = bid & 7;
    int u  = bid >> 3;
    int nt = u & 3;            // nt fastest: same-A blocks adjacent
    int mt = u >> 2;           // 0..63
    int s0, P;
    seg_of(cnt, e, s0, P);
    if (mt * 128 >= P) return;
    int p0 = s0 + mt * 128;

    __shared__ short As[2][128 * BK];
    __shared__ short Bs[2][128 * BK];

    int tid = threadIdx.x;
    int wv = tid >> 6, lane = tid & 63;
    int q = lane >> 4, r = lane & 15;
    int wm = wv >> 1, wn = wv & 1;

    const short* w2e = w2t + (size_t)e * D * H;

    const short* asrc[4];
    const short* bsrc[4];
#pragma unroll
    for (int p = 0; p < 4; ++p) {
        int g = p * 256 + tid;
        int row = g >> 3;
        int slot = (g & 7) ^ (row & 7);
        asrc[p] = hbuf + (size_t)(p0 + row) * H + slot * 8;
        bsrc[p] = w2e + (size_t)(nt * 128 + row) * H + slot * 8;
    }

    f32x4 acc[4][4];
#pragma unroll
    for (int m = 0; m < 4; ++m)
#pragma unroll
        for (int n = 0; n < 4; ++n) acc[m][n] = (f32x4){0.f, 0.f, 0.f, 0.f};

    const int xorv = r & 7;

#pragma unroll
    for (int p = 0; p < 4; ++p) {
        gll16(asrc[p], &As[0][p * 2048 + wv * 512]);   // A: cached (L3-resident hbuf)
        gll16(bsrc[p], &Bs[0][p * 2048 + wv * 512]);   // B panel: L2-resident
    }

    const int NTT = H / BK;   // 32
    for (int t = 0; t < NTT; ++t) {
        int b = t & 1;
        if (t + 1 < NTT) {
            int kk = (t + 1) * BK;
#pragma unroll
            for (int p = 0; p < 4; ++p) {
                gll16(asrc[p] + kk, &As[b ^ 1][p * 2048 + wv * 512]);
                gll16(bsrc[p] + kk, &Bs[b ^ 1][p * 2048 + wv * 512]);
            }
            asm volatile("s_waitcnt vmcnt(8)" ::: "memory");
        } else {
            asm volatile("s_waitcnt vmcnt(0)" ::: "memory");
        }
        __builtin_amdgcn_s_barrier();
        __builtin_amdgcn_sched_barrier(0);

        const char* Ab = (const char*)&As[b][0];
        const char* Bb = (const char*)&Bs[b][0];
#pragma unroll
        for (int ks = 0; ks < 2; ++ks) {
            int sslot = ((ks * 4 + q) ^ xorv) << 4;
            bf16x8 a[4], bb[4];
#pragma unroll
            for (int m = 0; m < 4; ++m)
                a[m] = *(const bf16x8*)(Ab + (wm * 64 + m * 16 + r) * 128 + sslot);
#pragma unroll
            for (int n = 0; n < 4; ++n)
                bb[n] = *(const bf16x8*)(Bb + (wn * 64 + n * 16 + r) * 128 + sslot);
            __builtin_amdgcn_s_setprio(1);
#pragma unroll
            for (int m = 0; m < 4; ++m)
#pragma unroll
                for (int n = 0; n < 4; ++n)
                    acc[m][n] = __builtin_amdgcn_mfma_f32_16x16x32_bf16(a[m], bb[n], acc[m][n], 0, 0, 0);
            __builtin_amdgcn_s_setprio(0);
        }
        if (t + 1 < NTT) {
            __builtin_amdgcn_s_barrier();
            __builtin_amdgcn_sched_barrier(0);
        }
    }
    __syncthreads();

    // -------- epilogue: bias -> slab -> coalesced 16B stores (cached) ----------
    const float* b2e = b2 + (size_t)e * D;
    float bv[4];
#pragma unroll
    for (int n = 0; n < 4; ++n) bv[n] = b2e[nt * 128 + wn * 64 + n * 16 + r];
    short* slab = &As[0][0];
#pragma unroll
    for (int m = 0; m < 4; ++m)
#pragma unroll
        for (int j = 0; j < 4; ++j) {
            int lr = wm * 64 + m * 16 + q * 4 + j;
#pragma unroll
            for (int n = 0; n < 4; ++n) {
                int col = wn * 64 + n * 16 + r;
                slab[lr * 128 + col] = f2b(acc[m][n][j] + bv[n]);
            }
        }
    __syncthreads();
#pragma unroll
    for (int p = 0; p < 8; ++p) {
        int idx = p * 256 + tid;
        int row = idx >> 4;
        int c16 = idx & 15;
        bf16x8 v = *reinterpret_cast<const bf16x8*>(&slab[row * 128 + c16 * 8]);
        *reinterpret_cast<bf16x8*>(&ybuf[(size_t)(p0 + row) * D + nt * 128 + c16 * 8]) = v;
    }
}

// ================= Combine: out[t] = w0*y[p0] + w1*y[p1] ======================
__global__ __launch_bounds__(256) void combine(
    const short* __restrict__ ybuf, const int* __restrict__ inv,
    const float2* __restrict__ wsel, float* __restrict__ out)
{
    int gid = blockIdx.x * 256 + threadIdx.x;
    int t  = gid >> 7;          // token
    int c4 = (gid & 127) * 4;   // col group
    float2 w = wsel[t];
    int i0 = inv[t * 2], i1 = inv[t * 2 + 1];
    short4 y0 = *reinterpret_cast<const short4*>(ybuf + (size_t)i0 * D + c4);
    short4 y1 = *reinterpret_cast<const short4*>(ybuf + (size_t)i1 * D + c4);
    float4 o;
    o.x = w.x * b2f(y0.x) + w.y * b2f(y1.x);
    o.y = w.x * b2f(y0.y) + w.y * b2f(y1.y);
    o.z = w.x * b2f(y0.z) + w.y * b2f(y1.z);
    o.w = w.x * b2f(y0.w) + w.y * b2f(y1.w);
    *reinterpret_cast<float4*>(out + (size_t)t * D + c4) = o;
}

// ---------------- Round-2 fused MFMA FFN (fallback if ws too small) ------------
#define TMM 64
#define FCC 64
#define XPAD 520
#define HPD 72

__global__ __launch_bounds__(512, 2) void ffn_mfma(
    const float* __restrict__ x,
    const short* __restrict__ w1t, const float* __restrict__ b1,
    const short* __restrict__ w2t, const float* __restrict__ b2,
    const int* __restrict__ cnt, const int* __restrict__ tok_id,
    const float* __restrict__ tok_w,
    float* __restrict__ out)
{
    int b = blockIdx.x;
    int e = b & 7;
    int tile = b >> 3;
    int n = cnt[e];
    int start = tile * TMM;
    if (start >= n) return;
    int nvalid = min(TMM, n - start);

    __shared__ short xs[TMM * XPAD];
    __shared__ short hs[TMM * HPD];
    __shared__ int   stok[TMM];
    __shared__ float sw[TMM];

    int tid = threadIdx.x;
    if (tid < TMM) {
        int tok = 0; float w = 0.f;
        if (tid < nvalid) {
            tok = tok_id[e * NTOK + start + tid];
            w   = tok_w[e * NTOK + start + tid];
        }
        stok[tid] = tok; sw[tid] = w;
    }
    __syncthreads();

    for (int idx = tid; idx < TMM * (D / 4); idx += 512) {
        int row = idx >> 7;
        int c4  = (idx & 127) << 2;
        float4 v = *reinterpret_cast<const float4*>(x + (size_t)stok[row] * D + c4);
        short4 o; o.x = f2b(v.x); o.y = f2b(v.y); o.z = f2b(v.z); o.w = f2b(v.w);
        *reinterpret_cast<short4*>(&xs[row * XPAD + c4]) = o;
    }
    __syncthreads();

    const int lane = tid & 63, wave = tid >> 6;
    const int wm = wave >> 2, wn = wave & 3;
    const int q = lane >> 4,  r = lane & 15;

    const short* w1e = w1t + (size_t)e * H * D;
    const short* w2e = w2t + (size_t)e * D * H;
    const float* b1e = b1 + (size_t)e * H;
    const float* b2e = b2 + (size_t)e * D;

    f32x4 acc[2][8];
#pragma unroll
    for (int i = 0; i < 2; ++i)
#pragma unroll
        for (int j = 0; j < 8; ++j) acc[i][j] = (f32x4){0.f, 0.f, 0.f, 0.f};

    for (int fc = 0; fc < H; fc += FCC) {
        int f = fc + wn * 16 + r;
        float b1f = b1e[f];
        f32x4 h0 = {b1f, b1f, b1f, b1f};
        f32x4 h1 = h0;
        const short* wrow = w1e + (size_t)f * D;
        const short* a0p = &xs[(wm * 32 + r) * XPAD + q * 8];
        const short* a1p = a0p + 16 * XPAD;
#pragma unroll
        for (int ks = 0; ks < 16; ++ks) {
            bf16x8 bfr = *reinterpret_cast<const bf16x8*>(wrow + ks * 32 + q * 8);
            bf16x8 a0  = *reinterpret_cast<const bf16x8*>(a0p + ks * 32);
            bf16x8 a1  = *reinterpret_cast<const bf16x8*>(a1p + ks * 32);
            h0 = __builtin_amdgcn_mfma_f32_16x16x32_bf16(a0, bfr, h0, 0, 0, 0);
            h1 = __builtin_amdgcn_mfma_f32_16x16x32_bf16(a1, bfr, h1, 0, 0, 0);
        }
        {
            int c = wn * 16 + r;
#pragma unroll
            for (int j = 0; j < 4; ++j) {
                hs[(wm * 32 + q * 4 + j) * HPD + c]      = f2b(gelu_exact(h0[j]));
                hs[(wm * 32 + 16 + q * 4 + j) * HPD + c] = f2b(gelu_exact(h1[j]));
            }
        }
        __syncthreads();
#pragma unroll
        for (int ks = 0; ks < 2; ++ks) {
            bf16x8 a20 = *reinterpret_cast<const bf16x8*>(&hs[(wm * 32 + r) * HPD + ks * 32 + q * 8]);
            bf16x8 a21 = *reinterpret_cast<const bf16x8*>(&hs[(wm * 32 + 16 + r) * HPD + ks * 32 + q * 8]);
#pragma unroll
            for (int nr = 0; nr < 8; ++nr) {
                int dout = wn * 128 + nr * 16 + r;
                bf16x8 bfr = *reinterpret_cast<const bf16x8*>(
                    w2e + (size_t)dout * H + fc + ks * 32 + q * 8);
                acc[0][nr] = __builtin_amdgcn_mfma_f32_16x16x32_bf16(a20, bfr, acc[0][nr], 0, 0, 0);
                acc[1][nr] = __builtin_amdgcn_mfma_f32_16x16x32_bf16(a21, bfr, acc[1][nr], 0, 0, 0);
            }
        }
        __syncthreads();
    }

#pragma unroll
    for (int mrep = 0; mrep < 2; ++mrep) {
#pragma unroll
        for (int j = 0; j < 4; ++j) {
            int rl = wm * 32 + mrep * 16 + q * 4 + j;
            if (rl < nvalid) {
                float w = sw[rl];
                if (w != 0.f) {
                    float* orow = out + (size_t)stok[rl] * D;
#pragma unroll
                    for (int nr = 0; nr < 8; ++nr) {
                        int dout = wn * 128 + nr * 16 + r;
                        f32x4 a = acc[mrep][nr];
                        atomicAdd(&orow[dout], w * (a[j] + b2e[dout]));
                    }
                }
            }
        }
    }
}

extern "C" void kernel_launch(void* const* d_in, const int* in_sizes, int n_in,
                              void* d_out, int out_size, void* d_ws, size_t ws_size,
                              hipStream_t stream) {
    const float* x  = (const float*)d_in[0];
    const float* ts = (const float*)d_in[1];
    const float* gw = (const float*)d_in[2];
    const float* gb = (const float*)d_in[3];
    const float* w1 = (const float*)d_in[4];
    const float* b1 = (const float*)d_in[5];
    const float* w2 = (const float*)d_in[6];
    const float* b2 = (const float*)d_in[7];
    float* out = (float*)d_out;

    // ws layout (bytes):
    // cnt@0 | tok_id@1024 (256K) | tok_w@263168 (256K) |
    // pad_tok@525312 (68K) | pad_w@594944 (68K) | sel@665600 (32K) |
    // wsel@700416 (64K) | inv@765952 (64K) | xbf@1M (8M) |
    // w1t@9437184 (16.78M) | w2t@26214400 (16.78M) | hbuf@42991616 (71.3M)
    // ybuf@1M (17.83M) overlays xbf+w1t — both dead after gemm1.
    int*    cnt     = (int*)d_ws;
    int*    tok_id  = (int*)((char*)d_ws + 1024);
    float*  tok_w   = (float*)((char*)d_ws + 263168);
    int*    pad_tok = (int*)((char*)d_ws + 525312);
    float*  pad_w   = (float*)((char*)d_ws + 594944);
    int*    sel     = (int*)((char*)d_ws + 665600);
    float2* wsel    = (float2*)((char*)d_ws + 700416);
    int*    inv     = (int*)((char*)d_ws + 765952);
    short*  xbf     = (short*)((char*)d_ws + 1048576);
    short*  w1t     = (short*)((char*)d_ws + 9437184);
    short*  w2t     = (short*)((char*)d_ws + 26214400);
    short*  hbuf    = (short*)((char*)d_ws + 42991616);
    short*  ybuf    = (short*)((char*)d_ws + 1048576);   // overlays xbf+w1t
    const size_t ws_need = 114294784;

    hipMemsetAsync(cnt, 0, 64, stream);

    if (ws_size >= ws_need) {
        router_score<<<NTOK / 4, 256, 0, stream>>>(x, ts, gw, gb, sel, wsel, xbf);
        scatter_tokens<<<NTOK / 256, 256, 0, stream>>>(sel, wsel, cnt, tok_id, tok_w);
        pad_fill<<<dim3(NTOK / 256, E), 256, 0, stream>>>(cnt, sel, tok_id, tok_w,
                                                          pad_tok, pad_w, inv);
        transpose_cvt2<<<dim3(8, 32, 2 * E), 256, 0, stream>>>(w1, w1t, w2, w2t);
        gemm1<<<E * 64 * 16, 256, 0, stream>>>(xbf, w1t, b1, cnt, pad_tok, hbuf);
        gemm2<<<E * 64 * 4, 256, 0, stream>>>(hbuf, w2t, b2, cnt, ybuf);
        combine<<<NTOK * (D / 4) / 256, 256, 0, stream>>>(ybuf, inv, wsel, out);
    } else {
        // fallback: round-2 layout (w1t@1M, w2t after)
        hipMemsetAsync(out, 0, (size_t)out_size * sizeof(float), stream);
        short* w1t_f = (short*)((char*)d_ws + (1u << 20));
        short* w2t_f = w1t_f + (size_t)E * D * H;
        router_kernel<<<NTOK / 256, 256, 0, stream>>>(x, ts, gw, gb, cnt, tok_id, tok_w);
        transpose_cvt2<<<dim3(8, 32, 2 * E), 256, 0, stream>>>(w1, w1t_f, w2, w2t_f);
        ffn_mfma<<<(NTOK / TMM) * E, 512, 0, stream>>>(
            x, w1t_f, b1, w2t_f, b2, cnt, tok_id, tok_w, out);
    }
}

// Round 16
// 188.182 us; speedup vs baseline: 1.3873x; 1.0110x over previous
//
#include <hip/hip_runtime.h>
#include <math.h>

#define D 512
#define H 2048
#define E 8
#define NTOK 8192
#define BK 64
#define PTMAX 17408   // capacity of pad_tok/pad_w arrays (rows)

typedef __attribute__((ext_vector_type(8))) short bf16x8;
typedef __attribute__((ext_vector_type(4))) float f32x4;

__device__ __forceinline__ short f2b(float v) {
    unsigned u = __float_as_uint(v);
    unsigned r = (u + 0x7FFFu + ((u >> 16) & 1u)) >> 16;  // RNE
    return (short)r;
}
__device__ __forceinline__ float b2f(short v) {
    unsigned u = ((unsigned)(unsigned short)v) << 16;
    return __uint_as_float(u);
}
__device__ __forceinline__ float gelu_exact(float v) {
    return 0.5f * v * (1.0f + erff(v * 0.70710678118654752f));
}
// tanh-form gelu via HW exp: max |err| ~1e-3 << bf16-h quantization.
__device__ __forceinline__ float gelu_fast(float v) {
    float u2 = -1.5957691216f * (v + 0.044715f * v * v * v);
    return v / (1.f + __expf(u2));
}
// async global->LDS, 16B per lane; LDS dest is wave-uniform base + lane*16
__device__ __forceinline__ void gll16(const void* g, void* l) {
    __builtin_amdgcn_global_load_lds(
        (const __attribute__((address_space(1))) void*)g,
        (__attribute__((address_space(3))) void*)l, 16, 0, 0);
}
// padded (128-aligned) prefix over cnt[]
__device__ __forceinline__ void seg_of(const int* cnt, int e, int& s0, int& P) {
    int o = 0;
#pragma unroll
    for (int i = 0; i < E; ++i) {
        int p = (cnt[i] + 127) & ~127;
        if (i < e) o += p;
        if (i == e) P = p;
    }
    s0 = o;
}

// ---------------- Router score: wave-per-token, NO global atomics --------------
__global__ __launch_bounds__(256) void router_score(
    const float* __restrict__ x, const float* __restrict__ ts,
    const float* __restrict__ gw, const float* __restrict__ gb,
    int* __restrict__ sel, float2* __restrict__ wsel,
    short* __restrict__ xbf)
{
    int wave = threadIdx.x >> 6, lane = threadIdx.x & 63;
    int t = blockIdx.x * 4 + wave;

    const float* xr = x + (size_t)t * D + lane * 8;
    const float* tr = ts + (size_t)t * D + lane * 8;
    float4 xa = *reinterpret_cast<const float4*>(xr);
    float4 xb = *reinterpret_cast<const float4*>(xr + 4);
    float4 ta = *reinterpret_cast<const float4*>(tr);
    float4 tb = *reinterpret_cast<const float4*>(tr + 4);

    bf16x8 o;
    o[0] = f2b(xa.x); o[1] = f2b(xa.y); o[2] = f2b(xa.z); o[3] = f2b(xa.w);
    o[4] = f2b(xb.x); o[5] = f2b(xb.y); o[6] = f2b(xb.z); o[7] = f2b(xb.w);
    *reinterpret_cast<bf16x8*>(xbf + (size_t)t * D + lane * 8) = o;

    float v[8] = {xa.x + ta.x, xa.y + ta.y, xa.z + ta.z, xa.w + ta.w,
                  xb.x + tb.x, xb.y + tb.y, xb.z + tb.z, xb.w + tb.w};
    float acc[E];
#pragma unroll
    for (int e2 = 0; e2 < E; ++e2) acc[e2] = 0.f;
#pragma unroll
    for (int i = 0; i < 8; ++i) {
        const float4* gr = reinterpret_cast<const float4*>(gw + (size_t)(lane * 8 + i) * E);
        float4 g0 = gr[0], g1 = gr[1];
        acc[0] += v[i] * g0.x; acc[1] += v[i] * g0.y; acc[2] += v[i] * g0.z; acc[3] += v[i] * g0.w;
        acc[4] += v[i] * g1.x; acc[5] += v[i] * g1.y; acc[6] += v[i] * g1.z; acc[7] += v[i] * g1.w;
    }
#pragma unroll
    for (int m = 32; m; m >>= 1) {
#pragma unroll
        for (int e2 = 0; e2 < E; ++e2) acc[e2] += __shfl_xor(acc[e2], m);
    }
    if (lane == 0) {
        float p[E]; float mx;
#pragma unroll
        for (int e2 = 0; e2 < E; ++e2) p[e2] = acc[e2] + gb[e2];
        mx = p[0];
#pragma unroll
        for (int e2 = 1; e2 < E; ++e2) mx = fmaxf(mx, p[e2]);
        float s = 0.f;
#pragma unroll
        for (int e2 = 0; e2 < E; ++e2) { p[e2] = expf(p[e2] - mx); s += p[e2]; }
        float inv = 1.f / s;
        int i0 = 0; float v0 = p[0];
#pragma unroll
        for (int e2 = 1; e2 < E; ++e2) if (p[e2] > v0) { v0 = p[e2]; i0 = e2; }
        int i1 = (i0 == 0) ? 1 : 0; float v1 = p[i1];
#pragma unroll
        for (int e2 = 0; e2 < E; ++e2)
            if (e2 != i0 && e2 != ((i0 == 0) ? 1 : 0) && p[e2] > v1) { v1 = p[e2]; i1 = e2; }
        sel[t]  = i0 | (i1 << 8);
        wsel[t] = make_float2(v0 * inv, v1 * inv);
    }
}

// ---------------- Scatter: block-aggregated buckets (256 global atomics) -------
__global__ __launch_bounds__(256) void scatter_tokens(
    const int* __restrict__ sel, const float2* __restrict__ wsel,
    int* __restrict__ cnt, int* __restrict__ tok_id, float* __restrict__ tok_w)
{
    __shared__ int lh[E];
    __shared__ int gbase[E];
    int tid = threadIdx.x;
    int t = blockIdx.x * 256 + tid;
    if (tid < E) lh[tid] = 0;
    __syncthreads();
    int s = sel[t];
    float2 w = wsel[t];
    int e0 = s & 255, e1 = s >> 8;
    int p0 = atomicAdd(&lh[e0], 1);
    int p1 = atomicAdd(&lh[e1], 1);
    __syncthreads();
    if (tid < E) gbase[tid] = atomicAdd(&cnt[tid], lh[tid]);
    __syncthreads();
    int o0 = gbase[e0] + p0;
    int o1 = gbase[e1] + p1;
    tok_id[e0 * NTOK + o0] = t;
    tok_w [e0 * NTOK + o0] = w.x;
    tok_id[e1 * NTOK + o1] = t;
    tok_w [e1 * NTOK + o1] = w.y;
}

// ---------------- Old router (fallback path, no xbf) ---------------------------
__global__ __launch_bounds__(256) void router_kernel(
    const float* __restrict__ x, const float* __restrict__ ts,
    const float* __restrict__ gw, const float* __restrict__ gb,
    int* __restrict__ cnt, int* __restrict__ tok_id, float* __restrict__ tok_w)
{
    int t = blockIdx.x * blockDim.x + threadIdx.x;
    if (t >= NTOK) return;
    float acc[E];
#pragma unroll
    for (int e = 0; e < E; ++e) acc[e] = gb[e];
    const float* xr = x + (size_t)t * D;
    const float* tr = ts + (size_t)t * D;
#pragma unroll 4
    for (int d = 0; d < D; ++d) {
        float xv = xr[d] + tr[d];
        const float4* g4 = reinterpret_cast<const float4*>(gw + d * E);
        float4 a = g4[0], b = g4[1];
        acc[0] += xv * a.x; acc[1] += xv * a.y; acc[2] += xv * a.z; acc[3] += xv * a.w;
        acc[4] += xv * b.x; acc[5] += xv * b.y; acc[6] += xv * b.z; acc[7] += xv * b.w;
    }
    float m = acc[0];
#pragma unroll
    for (int e = 1; e < E; ++e) m = fmaxf(m, acc[e]);
    float p[E]; float s = 0.f;
#pragma unroll
    for (int e = 0; e < E; ++e) { p[e] = expf(acc[e] - m); s += p[e]; }
    float inv = 1.f / s;
    int i0 = 0; float v0 = p[0];
#pragma unroll
    for (int e = 1; e < E; ++e) if (p[e] > v0) { v0 = p[e]; i0 = e; }
    int i1 = (i0 == 0) ? 1 : 0; float v1 = p[i1];
#pragma unroll
    for (int e = 0; e < E; ++e) if (e != i0 && e != ((i0 == 0) ? 1 : 0) && p[e] > v1) { v1 = p[e]; i1 = e; }
    int pos0 = atomicAdd(&cnt[i0], 1);
    tok_id[i0 * NTOK + pos0] = t;
    tok_w[i0 * NTOK + pos0] = v0 * inv;
    int pos1 = atomicAdd(&cnt[i1], 1);
    tok_id[i1 * NTOK + pos1] = t;
    tok_w[i1 * NTOK + pos1] = v1 * inv;
}

// ---------------- Prep: weight transposes + pad_fill in ONE launch -------------
// z<E: w1 transpose; z in [E,2E): w2 transpose; z==2E: pad_fill plane.
__global__ __launch_bounds__(256) void transpose_pad(
    const float* __restrict__ w1, short* __restrict__ w1t,
    const float* __restrict__ w2, short* __restrict__ w2t,
    const int* __restrict__ cnt, const int* __restrict__ sel,
    const int* __restrict__ tok_id, const float* __restrict__ tok_w,
    int* __restrict__ pad_tok, float* __restrict__ pad_w, int* __restrict__ inv)
{
    int z = blockIdx.z;
    int tid = threadIdx.x;
    if (z == 2 * E) {
        // pad_fill: e = bx (0..7), i = by*256+tid (0..8191)
        int e = blockIdx.x;
        int i = blockIdx.y * 256 + tid;
        int s, P;
        seg_of(cnt, e, s, P);
        if (i < P) {
            int n = cnt[e];
            int tok = (i < n) ? tok_id[e * NTOK + i] : 0;
            pad_tok[s + i] = tok;
            pad_w[s + i]   = (i < n) ? tok_w[e * NTOK + i] : 0.f;
            if (i < n) {
                int k = ((sel[tok] & 255) == e) ? 0 : 1;
                inv[tok * 2 + k] = s + i;
            }
        }
        return;
    }
    const float* src; short* dst; int R, C, rt, ct;
    if (z < E) {
        src = w1 + (size_t)z * D * H; dst = w1t + (size_t)z * D * H;
        R = D; C = H; rt = blockIdx.x * 64; ct = blockIdx.y * 64;
    } else {
        src = w2 + (size_t)(z - E) * H * D; dst = w2t + (size_t)(z - E) * H * D;
        R = H; C = D; rt = blockIdx.y * 64; ct = blockIdx.x * 64;
    }
    __shared__ float tsb[64][68];
    int r  = tid >> 4;
    int c4 = (tid & 15) * 4;
    for (int rr = r; rr < 64; rr += 16) {
        float4 v = *reinterpret_cast<const float4*>(src + (size_t)(rt + rr) * C + ct + c4);
        tsb[rr][c4] = v.x; tsb[rr][c4 + 1] = v.y; tsb[rr][c4 + 2] = v.z; tsb[rr][c4 + 3] = v.w;
    }
    __syncthreads();
    for (int cr = r; cr < 64; cr += 16) {
        short4 o;
        o.x = f2b(tsb[c4 + 0][cr]);
        o.y = f2b(tsb[c4 + 1][cr]);
        o.z = f2b(tsb[c4 + 2][cr]);
        o.w = f2b(tsb[c4 + 3][cr]);
        *reinterpret_cast<short4*>(dst + (size_t)(ct + cr) * R + rt + c4) = o;
    }
}

// ================= GEMM1: h = gelu(Xg @ W1 + b1) ==============================
// r13 shape: 128x128 tile, BK=64, 4 waves (2x2), 64KB LDS -> 2 blocks/CU,
// joint-prefetch counted vmcnt(8), T2 slot-swizzle, slab epilogue.
// New: single 32-MFMA cluster per K-step (all 16 fragments loaded up front).
__global__ __launch_bounds__(256, 2) void gemm1(
    const short* __restrict__ xbf,
    const short* __restrict__ w1t, const float* __restrict__ b1,
    const int* __restrict__ cnt, const int* __restrict__ pad_tok,
    short* __restrict__ hbuf)
{
    int bid = blockIdx.x;
    int e  = bid & 7;          // expert -> XCD affinity
    int u  = bid >> 3;
    int nt = u & 15;           // nt fastest: same-A blocks adjacent
    int mt = u >> 4;           // 0..63
    int s0, P;
    seg_of(cnt, e, s0, P);
    if (mt * 128 >= P) return;
    int p0 = s0 + mt * 128;    // P is 128-aligned -> tile always full

    __shared__ short As[2][128 * BK];   // 16 KB per buf; doubles as epilogue slab
    __shared__ short Bs[2][128 * BK];   // 64 KB total

    int tid = threadIdx.x;
    int wv = tid >> 6, lane = tid & 63;
    int q = lane >> 4, r = lane & 15;
    int wm = wv >> 1, wn = wv & 1;      // 2 x 2 wave grid, 64x64 per wave

    const short* w1e = w1t + (size_t)e * H * D;

    const short* asrc[4];
    const short* bsrc[4];
#pragma unroll
    for (int p = 0; p < 4; ++p) {
        int g = p * 256 + tid;
        int row = g >> 3;                      // 0..127
        int slot = (g & 7) ^ (row & 7);        // T2 swizzle on SOURCE
        int tok = pad_tok[p0 + row];
        asrc[p] = xbf + (size_t)tok * D + slot * 8;
        bsrc[p] = w1e + (size_t)(nt * 128 + row) * D + slot * 8;
    }

    f32x4 acc[4][4];
#pragma unroll
    for (int m = 0; m < 4; ++m)
#pragma unroll
        for (int n = 0; n < 4; ++n) acc[m][n] = (f32x4){0.f, 0.f, 0.f, 0.f};

    const int xorv = r & 7;

#pragma unroll
    for (int p = 0; p < 4; ++p) {
        gll16(asrc[p], &As[0][p * 2048 + wv * 512]);
        gll16(bsrc[p], &Bs[0][p * 2048 + wv * 512]);
    }

    const int NTT = D / BK;   // 8
    for (int t = 0; t < NTT; ++t) {
        int b = t & 1;
        if (t + 1 < NTT) {
            int kk = (t + 1) * BK;
#pragma unroll
            for (int p = 0; p < 4; ++p) {
                gll16(asrc[p] + kk, &As[b ^ 1][p * 2048 + wv * 512]);
                gll16(bsrc[p] + kk, &Bs[b ^ 1][p * 2048 + wv * 512]);
            }
            asm volatile("s_waitcnt vmcnt(8)" ::: "memory");
        } else {
            asm volatile("s_waitcnt vmcnt(0)" ::: "memory");
        }
        __builtin_amdgcn_s_barrier();
        __builtin_amdgcn_sched_barrier(0);

        const char* Ab = (const char*)&As[b][0];
        const char* Bb = (const char*)&Bs[b][0];
        // single 32-MFMA cluster: load all 16 fragments, then one setprio region
        bf16x8 a[8], bb[8];
#pragma unroll
        for (int ks = 0; ks < 2; ++ks) {
            int sslot = ((ks * 4 + q) ^ xorv) << 4;
#pragma unroll
            for (int m = 0; m < 4; ++m)
                a[ks * 4 + m] = *(const bf16x8*)(Ab + (wm * 64 + m * 16 + r) * 128 + sslot);
#pragma unroll
            for (int n = 0; n < 4; ++n)
                bb[ks * 4 + n] = *(const bf16x8*)(Bb + (wn * 64 + n * 16 + r) * 128 + sslot);
        }
        __builtin_amdgcn_s_setprio(1);
#pragma unroll
        for (int ks = 0; ks < 2; ++ks)
#pragma unroll
            for (int m = 0; m < 4; ++m)
#pragma unroll
                for (int n = 0; n < 4; ++n)
                    acc[m][n] = __builtin_amdgcn_mfma_f32_16x16x32_bf16(
                        a[ks * 4 + m], bb[ks * 4 + n], acc[m][n], 0, 0, 0);
        __builtin_amdgcn_s_setprio(0);
        if (t + 1 < NTT) {
            __builtin_amdgcn_s_barrier();
            __builtin_amdgcn_sched_barrier(0);
        }
    }
    __syncthreads();   // LDS reads done -> reuse As as 128x128 slab (32 KB)

    // -------- epilogue: gelu+bias -> slab -> coalesced 16B stores (cached) -----
    const float* b1e = b1 + (size_t)e * H;
    float bv[4];
#pragma unroll
    for (int n = 0; n < 4; ++n) bv[n] = b1e[nt * 128 + wn * 64 + n * 16 + r];
    short* slab = &As[0][0];
#pragma unroll
    for (int m = 0; m < 4; ++m)
#pragma unroll
        for (int j = 0; j < 4; ++j) {
            int lr = wm * 64 + m * 16 + q * 4 + j;
#pragma unroll
            for (int n = 0; n < 4; ++n) {
                int col = wn * 64 + n * 16 + r;
                slab[lr * 128 + col] = f2b(gelu_fast(acc[m][n][j] + bv[n]));
            }
        }
    __syncthreads();
#pragma unroll
    for (int p = 0; p < 8; ++p) {
        int idx = p * 256 + tid;       // 0..2047 = 128 rows x 16 chunks
        int row = idx >> 4;
        int c16 = idx & 15;
        bf16x8 v = *reinterpret_cast<const bf16x8*>(&slab[row * 128 + c16 * 8]);
        *reinterpret_cast<bf16x8*>(&hbuf[(size_t)(p0 + row) * H + nt * 128 + c16 * 8]) = v;
    }
}

// ================= GEMM2: y = h @ W2 + b2 (no atomics, cached A) ===============
__global__ __launch_bounds__(256, 2) void gemm2(
    const short* __restrict__ hbuf,
    const short* __restrict__ w2t, const float* __restrict__ b2,
    const int* __restrict__ cnt,
    short* __restrict__ ybuf)
{
    int bid = blockIdx.x;
    int e  = bid & 7;
    int u  = bid >> 3;
    int nt = u & 3;            // nt fastest: same-A blocks adjacent
    int mt = u >> 2;           // 0..63
    int s0, P;
    seg_of(cnt, e, s0, P);
    if (mt * 128 >= P) return;
    int p0 = s0 + mt * 128;

    __shared__ short As[2][128 * BK];
    __shared__ short Bs[2][128 * BK];

    int tid = threadIdx.x;
    int wv = tid >> 6, lane = tid & 63;
    int q = lane >> 4, r = lane & 15;
    int wm = wv >> 1, wn = wv & 1;

    const short* w2e = w2t + (size_t)e * D * H;

    const short* asrc[4];
    const short* bsrc[4];
#pragma unroll
    for (int p = 0; p < 4; ++p) {
        int g = p * 256 + tid;
        int row = g >> 3;
        int slot = (g & 7) ^ (row & 7);
        asrc[p] = hbuf + (size_t)(p0 + row) * H + slot * 8;
        bsrc[p] = w2e + (size_t)(nt * 128 + row) * H + slot * 8;
    }

    f32x4 acc[4][4];
#pragma unroll
    for (int m = 0; m < 4; ++m)
#pragma unroll
        for (int n = 0; n < 4; ++n) acc[m][n] = (f32x4){0.f, 0.f, 0.f, 0.f};

    const int xorv = r & 7;

#pragma unroll
    for (int p = 0; p < 4; ++p) {
        gll16(asrc[p], &As[0][p * 2048 + wv * 512]);   // A: cached (L3-resident hbuf)
        gll16(bsrc[p], &Bs[0][p * 2048 + wv * 512]);   // B panel: L2-resident
    }

    const int NTT = H / BK;   // 32
    for (int t = 0; t < NTT; ++t) {
        int b = t & 1;
        if (t + 1 < NTT) {
            int kk = (t + 1) * BK;
#pragma unroll
            for (int p = 0; p < 4; ++p) {
                gll16(asrc[p] + kk, &As[b ^ 1][p * 2048 + wv * 512]);
                gll16(bsrc[p] + kk, &Bs[b ^ 1][p * 2048 + wv * 512]);
            }
            asm volatile("s_waitcnt vmcnt(8)" ::: "memory");
        } else {
            asm volatile("s_waitcnt vmcnt(0)" ::: "memory");
        }
        __builtin_amdgcn_s_barrier();
        __builtin_amdgcn_sched_barrier(0);

        const char* Ab = (const char*)&As[b][0];
        const char* Bb = (const char*)&Bs[b][0];
        bf16x8 a[8], bb[8];
#pragma unroll
        for (int ks = 0; ks < 2; ++ks) {
            int sslot = ((ks * 4 + q) ^ xorv) << 4;
#pragma unroll
            for (int m = 0; m < 4; ++m)
                a[ks * 4 + m] = *(const bf16x8*)(Ab + (wm * 64 + m * 16 + r) * 128 + sslot);
#pragma unroll
            for (int n = 0; n < 4; ++n)
                bb[ks * 4 + n] = *(const bf16x8*)(Bb + (wn * 64 + n * 16 + r) * 128 + sslot);
        }
        __builtin_amdgcn_s_setprio(1);
#pragma unroll
        for (int ks = 0; ks < 2; ++ks)
#pragma unroll
            for (int m = 0; m < 4; ++m)
#pragma unroll
                for (int n = 0; n < 4; ++n)
                    acc[m][n] = __builtin_amdgcn_mfma_f32_16x16x32_bf16(
                        a[ks * 4 + m], bb[ks * 4 + n], acc[m][n], 0, 0, 0);
        __builtin_amdgcn_s_setprio(0);
        if (t + 1 < NTT) {
            __builtin_amdgcn_s_barrier();
            __builtin_amdgcn_sched_barrier(0);
        }
    }
    __syncthreads();

    // -------- epilogue: bias -> slab -> coalesced 16B stores (cached) ----------
    const float* b2e = b2 + (size_t)e * D;
    float bv[4];
#pragma unroll
    for (int n = 0; n < 4; ++n) bv[n] = b2e[nt * 128 + wn * 64 + n * 16 + r];
    short* slab = &As[0][0];
#pragma unroll
    for (int m = 0; m < 4; ++m)
#pragma unroll
        for (int j = 0; j < 4; ++j) {
            int lr = wm * 64 + m * 16 + q * 4 + j;
#pragma unroll
            for (int n = 0; n < 4; ++n) {
                int col = wn * 64 + n * 16 + r;
                slab[lr * 128 + col] = f2b(acc[m][n][j] + bv[n]);
            }
        }
    __syncthreads();
#pragma unroll
    for (int p = 0; p < 8; ++p) {
        int idx = p * 256 + tid;
        int row = idx >> 4;
        int c16 = idx & 15;
        bf16x8 v = *reinterpret_cast<const bf16x8*>(&slab[row * 128 + c16 * 8]);
        *reinterpret_cast<bf16x8*>(&ybuf[(size_t)(p0 + row) * D + nt * 128 + c16 * 8]) = v;
    }
}

// ================= Combine: out[t] = w0*y[p0] + w1*y[p1] ======================
__global__ __launch_bounds__(256) void combine(
    const short* __restrict__ ybuf, const int* __restrict__ inv,
    const float2* __restrict__ wsel, float* __restrict__ out)
{
    int gid = blockIdx.x * 256 + threadIdx.x;
    int t  = gid >> 7;          // token
    int c4 = (gid & 127) * 4;   // col group
    float2 w = wsel[t];
    int i0 = inv[t * 2], i1 = inv[t * 2 + 1];
    short4 y0 = *reinterpret_cast<const short4*>(ybuf + (size_t)i0 * D + c4);
    short4 y1 = *reinterpret_cast<const short4*>(ybuf + (size_t)i1 * D + c4);
    float4 o;
    o.x = w.x * b2f(y0.x) + w.y * b2f(y1.x);
    o.y = w.x * b2f(y0.y) + w.y * b2f(y1.y);
    o.z = w.x * b2f(y0.z) + w.y * b2f(y1.z);
    o.w = w.x * b2f(y0.w) + w.y * b2f(y1.w);
    *reinterpret_cast<float4*>(out + (size_t)t * D + c4) = o;
}

// ---------------- Round-2 fused MFMA FFN (fallback if ws too small) ------------
#define TMM 64
#define FCC 64
#define XPAD 520
#define HPD 72

__global__ __launch_bounds__(512, 2) void ffn_mfma(
    const float* __restrict__ x,
    const short* __restrict__ w1t, const float* __restrict__ b1,
    const short* __restrict__ w2t, const float* __restrict__ b2,
    const int* __restrict__ cnt, const int* __restrict__ tok_id,
    const float* __restrict__ tok_w,
    float* __restrict__ out)
{
    int b = blockIdx.x;
    int e = b & 7;
    int tile = b >> 3;
    int n = cnt[e];
    int start = tile * TMM;
    if (start >= n) return;
    int nvalid = min(TMM, n - start);

    __shared__ short xs[TMM * XPAD];
    __shared__ short hs[TMM * HPD];
    __shared__ int   stok[TMM];
    __shared__ float sw[TMM];

    int tid = threadIdx.x;
    if (tid < TMM) {
        int tok = 0; float w = 0.f;
        if (tid < nvalid) {
            tok = tok_id[e * NTOK + start + tid];
            w   = tok_w[e * NTOK + start + tid];
        }
        stok[tid] = tok; sw[tid] = w;
    }
    __syncthreads();

    for (int idx = tid; idx < TMM * (D / 4); idx += 512) {
        int row = idx >> 7;
        int c4  = (idx & 127) << 2;
        float4 v = *reinterpret_cast<const float4*>(x + (size_t)stok[row] * D + c4);
        short4 o; o.x = f2b(v.x); o.y = f2b(v.y); o.z = f2b(v.z); o.w = f2b(v.w);
        *reinterpret_cast<short4*>(&xs[row * XPAD + c4]) = o;
    }
    __syncthreads();

    const int lane = tid & 63, wave = tid >> 6;
    const int wm = wave >> 2, wn = wave & 3;
    const int q = lane >> 4,  r = lane & 15;

    const short* w1e = w1t + (size_t)e * H * D;
    const short* w2e = w2t + (size_t)e * D * H;
    const float* b1e = b1 + (size_t)e * H;
    const float* b2e = b2 + (size_t)e * D;

    f32x4 acc[2][8];
#pragma unroll
    for (int i = 0; i < 2; ++i)
#pragma unroll
        for (int j = 0; j < 8; ++j) acc[i][j] = (f32x4){0.f, 0.f, 0.f, 0.f};

    for (int fc = 0; fc < H; fc += FCC) {
        int f = fc + wn * 16 + r;
        float b1f = b1e[f];
        f32x4 h0 = {b1f, b1f, b1f, b1f};
        f32x4 h1 = h0;
        const short* wrow = w1e + (size_t)f * D;
        const short* a0p = &xs[(wm * 32 + r) * XPAD + q * 8];
        const short* a1p = a0p + 16 * XPAD;
#pragma unroll
        for (int ks = 0; ks < 16; ++ks) {
            bf16x8 bfr = *reinterpret_cast<const bf16x8*>(wrow + ks * 32 + q * 8);
            bf16x8 a0  = *reinterpret_cast<const bf16x8*>(a0p + ks * 32);
            bf16x8 a1  = *reinterpret_cast<const bf16x8*>(a1p + ks * 32);
            h0 = __builtin_amdgcn_mfma_f32_16x16x32_bf16(a0, bfr, h0, 0, 0, 0);
            h1 = __builtin_amdgcn_mfma_f32_16x16x32_bf16(a1, bfr, h1, 0, 0, 0);
        }
        {
            int c = wn * 16 + r;
#pragma unroll
            for (int j = 0; j < 4; ++j) {
                hs[(wm * 32 + q * 4 + j) * HPD + c]      = f2b(gelu_exact(h0[j]));
                hs[(wm * 32 + 16 + q * 4 + j) * HPD + c] = f2b(gelu_exact(h1[j]));
            }
        }
        __syncthreads();
#pragma unroll
        for (int ks = 0; ks < 2; ++ks) {
            bf16x8 a20 = *reinterpret_cast<const bf16x8*>(&hs[(wm * 32 + r) * HPD + ks * 32 + q * 8]);
            bf16x8 a21 = *reinterpret_cast<const bf16x8*>(&hs[(wm * 32 + 16 + r) * HPD + ks * 32 + q * 8]);
#pragma unroll
            for (int nr = 0; nr < 8; ++nr) {
                int dout = wn * 128 + nr * 16 + r;
                bf16x8 bfr = *reinterpret_cast<const bf16x8*>(
                    w2e + (size_t)dout * H + fc + ks * 32 + q * 8);
                acc[0][nr] = __builtin_amdgcn_mfma_f32_16x16x32_bf16(a20, bfr, acc[0][nr], 0, 0, 0);
                acc[1][nr] = __builtin_amdgcn_mfma_f32_16x16x32_bf16(a21, bfr, acc[1][nr], 0, 0, 0);
            }
        }
        __syncthreads();
    }

#pragma unroll
    for (int mrep = 0; mrep < 2; ++mrep) {
#pragma unroll
        for (int j = 0; j < 4; ++j) {
            int rl = wm * 32 + mrep * 16 + q * 4 + j;
            if (rl < nvalid) {
                float w = sw[rl];
                if (w != 0.f) {
                    float* orow = out + (size_t)stok[rl] * D;
#pragma unroll
                    for (int nr = 0; nr < 8; ++nr) {
                        int dout = wn * 128 + nr * 16 + r;
                        f32x4 a = acc[mrep][nr];
                        atomicAdd(&orow[dout], w * (a[j] + b2e[dout]));
                    }
                }
            }
        }
    }
}

extern "C" void kernel_launch(void* const* d_in, const int* in_sizes, int n_in,
                              void* d_out, int out_size, void* d_ws, size_t ws_size,
                              hipStream_t stream) {
    const float* x  = (const float*)d_in[0];
    const float* ts = (const float*)d_in[1];
    const float* gw = (const float*)d_in[2];
    const float* gb = (const float*)d_in[3];
    const float* w1 = (const float*)d_in[4];
    const float* b1 = (const float*)d_in[5];
    const float* w2 = (const float*)d_in[6];
    const float* b2 = (const float*)d_in[7];
    float* out = (float*)d_out;

    // ws layout (bytes):
    // cnt@0 | tok_id@1024 (256K) | tok_w@263168 (256K) |
    // pad_tok@525312 (68K) | pad_w@594944 (68K) | sel@665600 (32K) |
    // wsel@700416 (64K) | inv@765952 (64K) | xbf@1M (8M) |
    // w1t@9437184 (16.78M) | w2t@26214400 (16.78M) | hbuf@42991616 (71.3M)
    // ybuf@1M (17.83M) overlays xbf+w1t — both dead after gemm1.
    int*    cnt     = (int*)d_ws;
    int*    tok_id  = (int*)((char*)d_ws + 1024);
    float*  tok_w   = (float*)((char*)d_ws + 263168);
    int*    pad_tok = (int*)((char*)d_ws + 525312);
    float*  pad_w   = (float*)((char*)d_ws + 594944);
    int*    sel     = (int*)((char*)d_ws + 665600);
    float2* wsel    = (float2*)((char*)d_ws + 700416);
    int*    inv     = (int*)((char*)d_ws + 765952);
    short*  xbf     = (short*)((char*)d_ws + 1048576);
    short*  w1t     = (short*)((char*)d_ws + 9437184);
    short*  w2t     = (short*)((char*)d_ws + 26214400);
    short*  hbuf    = (short*)((char*)d_ws + 42991616);
    short*  ybuf    = (short*)((char*)d_ws + 1048576);   // overlays xbf+w1t
    const size_t ws_need = 114294784;

    hipMemsetAsync(cnt, 0, 64, stream);

    if (ws_size >= ws_need) {
        router_score<<<NTOK / 4, 256, 0, stream>>>(x, ts, gw, gb, sel, wsel, xbf);
        scatter_tokens<<<NTOK / 256, 256, 0, stream>>>(sel, wsel, cnt, tok_id, tok_w);
        transpose_pad<<<dim3(8, 32, 2 * E + 1), 256, 0, stream>>>(
            w1, w1t, w2, w2t, cnt, sel, tok_id, tok_w, pad_tok, pad_w, inv);
        gemm1<<<E * 64 * 16, 256, 0, stream>>>(xbf, w1t, b1, cnt, pad_tok, hbuf);
        gemm2<<<E * 64 * 4, 256, 0, stream>>>(hbuf, w2t, b2, cnt, ybuf);
        combine<<<NTOK * (D / 4) / 256, 256, 0, stream>>>(ybuf, inv, wsel, out);
    } else {
        // fallback: round-2 layout (w1t@1M, w2t after)
        hipMemsetAsync(out, 0, (size_t)out_size * sizeof(float), stream);
        short* w1t_f = (short*)((char*)d_ws + (1u << 20));
        short* w2t_f = w1t_f + (size_t)E * D * H;
        router_kernel<<<NTOK / 256, 256, 0, stream>>>(x, ts, gw, gb, cnt, tok_id, tok_w);
        transpose_pad<<<dim3(8, 32, 2 * E), 256, 0, stream>>>(
            w1, w1t_f, w2, w2t_f, cnt, nullptr, nullptr, nullptr,
            nullptr, nullptr, nullptr);
        ffn_mfma<<<(NTOK / TMM) * E, 512, 0, stream>>>(
            x, w1t_f, b1, w2t_f, b2, cnt, tok_id, tok_w, out);
    }
}

// Round 17
// 160.840 us; speedup vs baseline: 1.6231x; 1.1700x over previous
//
#include <hip/hip_runtime.h>
#include <math.h>

#define D 512
#define H 2048
#define E 8
#define NTOK 8192
#define BK 64
#define PTMAX 17408   // capacity of pad_tok/pad_w arrays (rows)

typedef __attribute__((ext_vector_type(8))) short bf16x8;
typedef __attribute__((ext_vector_type(4))) float f32x4;

__device__ __forceinline__ short f2b(float v) {
    unsigned u = __float_as_uint(v);
    unsigned r = (u + 0x7FFFu + ((u >> 16) & 1u)) >> 16;  // RNE
    return (short)r;
}
__device__ __forceinline__ float b2f(short v) {
    unsigned u = ((unsigned)(unsigned short)v) << 16;
    return __uint_as_float(u);
}
__device__ __forceinline__ float gelu_exact(float v) {
    return 0.5f * v * (1.0f + erff(v * 0.70710678118654752f));
}
// tanh-form gelu via HW exp: max |err| ~1e-3 << bf16-h quantization.
__device__ __forceinline__ float gelu_fast(float v) {
    float u2 = -1.5957691216f * (v + 0.044715f * v * v * v);
    return v / (1.f + __expf(u2));
}
// padded (128-aligned) prefix over cnt[]
__device__ __forceinline__ void seg_of(const int* cnt, int e, int& s0, int& P) {
    int o = 0;
#pragma unroll
    for (int i = 0; i < E; ++i) {
        int p = (cnt[i] + 127) & ~127;
        if (i < e) o += p;
        if (i == e) P = p;
    }
    s0 = o;
}

// ---------------- Router score: wave-per-token, NO global atomics --------------
__global__ __launch_bounds__(256) void router_score(
    const float* __restrict__ x, const float* __restrict__ ts,
    const float* __restrict__ gw, const float* __restrict__ gb,
    int* __restrict__ sel, float2* __restrict__ wsel,
    short* __restrict__ xbf)
{
    int wave = threadIdx.x >> 6, lane = threadIdx.x & 63;
    int t = blockIdx.x * 4 + wave;

    const float* xr = x + (size_t)t * D + lane * 8;
    const float* tr = ts + (size_t)t * D + lane * 8;
    float4 xa = *reinterpret_cast<const float4*>(xr);
    float4 xb = *reinterpret_cast<const float4*>(xr + 4);
    float4 ta = *reinterpret_cast<const float4*>(tr);
    float4 tb = *reinterpret_cast<const float4*>(tr + 4);

    bf16x8 o;
    o[0] = f2b(xa.x); o[1] = f2b(xa.y); o[2] = f2b(xa.z); o[3] = f2b(xa.w);
    o[4] = f2b(xb.x); o[5] = f2b(xb.y); o[6] = f2b(xb.z); o[7] = f2b(xb.w);
    *reinterpret_cast<bf16x8*>(xbf + (size_t)t * D + lane * 8) = o;

    float v[8] = {xa.x + ta.x, xa.y + ta.y, xa.z + ta.z, xa.w + ta.w,
                  xb.x + tb.x, xb.y + tb.y, xb.z + tb.z, xb.w + tb.w};
    float acc[E];
#pragma unroll
    for (int e2 = 0; e2 < E; ++e2) acc[e2] = 0.f;
#pragma unroll
    for (int i = 0; i < 8; ++i) {
        const float4* gr = reinterpret_cast<const float4*>(gw + (size_t)(lane * 8 + i) * E);
        float4 g0 = gr[0], g1 = gr[1];
        acc[0] += v[i] * g0.x; acc[1] += v[i] * g0.y; acc[2] += v[i] * g0.z; acc[3] += v[i] * g0.w;
        acc[4] += v[i] * g1.x; acc[5] += v[i] * g1.y; acc[6] += v[i] * g1.z; acc[7] += v[i] * g1.w;
    }
#pragma unroll
    for (int m = 32; m; m >>= 1) {
#pragma unroll
        for (int e2 = 0; e2 < E; ++e2) acc[e2] += __shfl_xor(acc[e2], m);
    }
    if (lane == 0) {
        float p[E]; float mx;
#pragma unroll
        for (int e2 = 0; e2 < E; ++e2) p[e2] = acc[e2] + gb[e2];
        mx = p[0];
#pragma unroll
        for (int e2 = 1; e2 < E; ++e2) mx = fmaxf(mx, p[e2]);
        float s = 0.f;
#pragma unroll
        for (int e2 = 0; e2 < E; ++e2) { p[e2] = expf(p[e2] - mx); s += p[e2]; }
        float inv = 1.f / s;
        int i0 = 0; float v0 = p[0];
#pragma unroll
        for (int e2 = 1; e2 < E; ++e2) if (p[e2] > v0) { v0 = p[e2]; i0 = e2; }
        int i1 = (i0 == 0) ? 1 : 0; float v1 = p[i1];
#pragma unroll
        for (int e2 = 0; e2 < E; ++e2)
            if (e2 != i0 && e2 != ((i0 == 0) ? 1 : 0) && p[e2] > v1) { v1 = p[e2]; i1 = e2; }
        sel[t]  = i0 | (i1 << 8);
        wsel[t] = make_float2(v0 * inv, v1 * inv);
    }
}

// ---------------- Scatter: block-aggregated buckets (256 global atomics) -------
__global__ __launch_bounds__(256) void scatter_tokens(
    const int* __restrict__ sel, const float2* __restrict__ wsel,
    int* __restrict__ cnt, int* __restrict__ tok_id, float* __restrict__ tok_w)
{
    __shared__ int lh[E];
    __shared__ int gbase[E];
    int tid = threadIdx.x;
    int t = blockIdx.x * 256 + tid;
    if (tid < E) lh[tid] = 0;
    __syncthreads();
    int s = sel[t];
    float2 w = wsel[t];
    int e0 = s & 255, e1 = s >> 8;
    int p0 = atomicAdd(&lh[e0], 1);
    int p1 = atomicAdd(&lh[e1], 1);
    __syncthreads();
    if (tid < E) gbase[tid] = atomicAdd(&cnt[tid], lh[tid]);
    __syncthreads();
    int o0 = gbase[e0] + p0;
    int o1 = gbase[e1] + p1;
    tok_id[e0 * NTOK + o0] = t;
    tok_w [e0 * NTOK + o0] = w.x;
    tok_id[e1 * NTOK + o1] = t;
    tok_w [e1 * NTOK + o1] = w.y;
}

// ---------------- Old router (fallback path, no xbf) ---------------------------
__global__ __launch_bounds__(256) void router_kernel(
    const float* __restrict__ x, const float* __restrict__ ts,
    const float* __restrict__ gw, const float* __restrict__ gb,
    int* __restrict__ cnt, int* __restrict__ tok_id, float* __restrict__ tok_w)
{
    int t = blockIdx.x * blockDim.x + threadIdx.x;
    if (t >= NTOK) return;
    float acc[E];
#pragma unroll
    for (int e = 0; e < E; ++e) acc[e] = gb[e];
    const float* xr = x + (size_t)t * D;
    const float* tr = ts + (size_t)t * D;
#pragma unroll 4
    for (int d = 0; d < D; ++d) {
        float xv = xr[d] + tr[d];
        const float4* g4 = reinterpret_cast<const float4*>(gw + d * E);
        float4 a = g4[0], b = g4[1];
        acc[0] += xv * a.x; acc[1] += xv * a.y; acc[2] += xv * a.z; acc[3] += xv * a.w;
        acc[4] += xv * b.x; acc[5] += xv * b.y; acc[6] += xv * b.z; acc[7] += xv * b.w;
    }
    float m = acc[0];
#pragma unroll
    for (int e = 1; e < E; ++e) m = fmaxf(m, acc[e]);
    float p[E]; float s = 0.f;
#pragma unroll
    for (int e = 0; e < E; ++e) { p[e] = expf(acc[e] - m); s += p[e]; }
    float inv = 1.f / s;
    int i0 = 0; float v0 = p[0];
#pragma unroll
    for (int e = 1; e < E; ++e) if (p[e] > v0) { v0 = p[e]; i0 = e; }
    int i1 = (i0 == 0) ? 1 : 0; float v1 = p[i1];
#pragma unroll
    for (int e = 0; e < E; ++e) if (e != i0 && e != ((i0 == 0) ? 1 : 0) && p[e] > v1) { v1 = p[e]; i1 = e; }
    int pos0 = atomicAdd(&cnt[i0], 1);
    tok_id[i0 * NTOK + pos0] = t;
    tok_w[i0 * NTOK + pos0] = v0 * inv;
    int pos1 = atomicAdd(&cnt[i1], 1);
    tok_id[i1 * NTOK + pos1] = t;
    tok_w[i1 * NTOK + pos1] = v1 * inv;
}

// ---------------- Prep: weight transposes + pad_fill in ONE launch -------------
__global__ __launch_bounds__(256) void transpose_pad(
    const float* __restrict__ w1, short* __restrict__ w1t,
    const float* __restrict__ w2, short* __restrict__ w2t,
    const int* __restrict__ cnt, const int* __restrict__ sel,
    const int* __restrict__ tok_id, const float* __restrict__ tok_w,
    int* __restrict__ pad_tok, float* __restrict__ pad_w, int* __restrict__ inv)
{
    int z = blockIdx.z;
    int tid = threadIdx.x;
    if (z == 2 * E) {
        int e = blockIdx.x;
        int i = blockIdx.y * 256 + tid;
        int s, P;
        seg_of(cnt, e, s, P);
        if (i < P) {
            int n = cnt[e];
            int tok = (i < n) ? tok_id[e * NTOK + i] : 0;
            pad_tok[s + i] = tok;
            pad_w[s + i]   = (i < n) ? tok_w[e * NTOK + i] : 0.f;
            if (i < n) {
                int k = ((sel[tok] & 255) == e) ? 0 : 1;
                inv[tok * 2 + k] = s + i;
            }
        }
        return;
    }
    const float* src; short* dst; int R, C, rt, ct;
    if (z < E) {
        src = w1 + (size_t)z * D * H; dst = w1t + (size_t)z * D * H;
        R = D; C = H; rt = blockIdx.x * 64; ct = blockIdx.y * 64;
    } else {
        src = w2 + (size_t)(z - E) * H * D; dst = w2t + (size_t)(z - E) * H * D;
        R = H; C = D; rt = blockIdx.y * 64; ct = blockIdx.x * 64;
    }
    __shared__ float tsb[64][68];
    int r  = tid >> 4;
    int c4 = (tid & 15) * 4;
    for (int rr = r; rr < 64; rr += 16) {
        float4 v = *reinterpret_cast<const float4*>(src + (size_t)(rt + rr) * C + ct + c4);
        tsb[rr][c4] = v.x; tsb[rr][c4 + 1] = v.y; tsb[rr][c4 + 2] = v.z; tsb[rr][c4 + 3] = v.w;
    }
    __syncthreads();
    for (int cr = r; cr < 64; cr += 16) {
        short4 o;
        o.x = f2b(tsb[c4 + 0][cr]);
        o.y = f2b(tsb[c4 + 1][cr]);
        o.z = f2b(tsb[c4 + 2][cr]);
        o.w = f2b(tsb[c4 + 3][cr]);
        *reinterpret_cast<short4*>(dst + (size_t)(ct + cr) * R + rt + c4) = o;
    }
}

// ================= GEMM1: h = gelu(Xg @ W1 + b1) ==============================
// 128x128 tile, BK=64, 4 waves, SINGLE 32KB LDS buffer + reg-staged prefetch
// (T14 split: issue loads t+1 -> compute t -> barrier -> ds_write t+1).
// 3 blocks/CU target (constant grain, +50% co-residency vs r13's gll16 dbuf).
__global__ __launch_bounds__(256, 3) void gemm1(
    const short* __restrict__ xbf,
    const short* __restrict__ w1t, const float* __restrict__ b1,
    const int* __restrict__ cnt, const int* __restrict__ pad_tok,
    short* __restrict__ hbuf)
{
    int bid = blockIdx.x;
    int e  = bid & 7;          // expert -> XCD affinity
    int u  = bid >> 3;
    int nt = u & 15;           // nt fastest: same-A blocks adjacent
    int mt = u >> 4;           // 0..63
    int s0, P;
    seg_of(cnt, e, s0, P);
    if (mt * 128 >= P) return;
    int p0 = s0 + mt * 128;    // P is 128-aligned -> tile always full

    __shared__ short lds[16384];  // A @0 (8192 shorts), B @8192; also 128x128 slab

    int tid = threadIdx.x;
    int lane = tid & 63;
    int wv = tid >> 6;
    int q = lane >> 4, r = lane & 15;
    int wm = wv >> 1, wn = wv & 1;      // 2 x 2 wave grid, 64x64 per wave

    const short* w1e = w1t + (size_t)e * H * D;

    const short* asrc[4];
    const short* bsrc[4];
#pragma unroll
    for (int p = 0; p < 4; ++p) {
        int g = p * 256 + tid;
        int row = g >> 3;                      // 0..127
        int slot = (g & 7) ^ (row & 7);        // T2 swizzle on SOURCE
        int tok = pad_tok[p0 + row];
        asrc[p] = xbf + (size_t)tok * D + slot * 8;
        bsrc[p] = w1e + (size_t)(nt * 128 + row) * D + slot * 8;
    }

    f32x4 acc[4][4];
#pragma unroll
    for (int m = 0; m < 4; ++m)
#pragma unroll
        for (int n = 0; n < 4; ++n) acc[m][n] = (f32x4){0.f, 0.f, 0.f, 0.f};

    const int xorv = r & 7;
    const int lw = tid * 8;   // thread's LDS write offset within a p-chunk

    bf16x8 ra[4], rb[4];
    // prologue: load tile 0 to regs, write to LDS
#pragma unroll
    for (int p = 0; p < 4; ++p) {
        ra[p] = *reinterpret_cast<const bf16x8*>(asrc[p]);
        rb[p] = *reinterpret_cast<const bf16x8*>(bsrc[p]);
    }
#pragma unroll
    for (int p = 0; p < 4; ++p) {
        *reinterpret_cast<bf16x8*>(&lds[p * 2048 + lw])        = ra[p];
        *reinterpret_cast<bf16x8*>(&lds[8192 + p * 2048 + lw]) = rb[p];
    }
    asm volatile("s_waitcnt lgkmcnt(0)" ::: "memory");

    const int NTT = D / BK;   // 8
    for (int t = 0; t < NTT; ++t) {
        if (t + 1 < NTT) {
            int kk = (t + 1) * BK;
#pragma unroll
            for (int p = 0; p < 4; ++p) {
                ra[p] = *reinterpret_cast<const bf16x8*>(asrc[p] + kk);
                rb[p] = *reinterpret_cast<const bf16x8*>(bsrc[p] + kk);
            }
        }
        __builtin_amdgcn_s_barrier();        // tile t visible to all waves
        __builtin_amdgcn_sched_barrier(0);

        const char* Ab = (const char*)&lds[0];
        const char* Bb = (const char*)&lds[8192];
#pragma unroll
        for (int ks = 0; ks < 2; ++ks) {
            int sslot = ((ks * 4 + q) ^ xorv) << 4;
            bf16x8 a[4], bb[4];
#pragma unroll
            for (int m = 0; m < 4; ++m)
                a[m] = *(const bf16x8*)(Ab + (wm * 64 + m * 16 + r) * 128 + sslot);
#pragma unroll
            for (int n = 0; n < 4; ++n)
                bb[n] = *(const bf16x8*)(Bb + (wn * 64 + n * 16 + r) * 128 + sslot);
            __builtin_amdgcn_s_setprio(1);
#pragma unroll
            for (int m = 0; m < 4; ++m)
#pragma unroll
                for (int n = 0; n < 4; ++n)
                    acc[m][n] = __builtin_amdgcn_mfma_f32_16x16x32_bf16(a[m], bb[n], acc[m][n], 0, 0, 0);
            __builtin_amdgcn_s_setprio(0);
        }
        __builtin_amdgcn_s_barrier();        // all reads of tile t done
        __builtin_amdgcn_sched_barrier(0);
        if (t + 1 < NTT) {
#pragma unroll
            for (int p = 0; p < 4; ++p) {
                *reinterpret_cast<bf16x8*>(&lds[p * 2048 + lw])        = ra[p];
                *reinterpret_cast<bf16x8*>(&lds[8192 + p * 2048 + lw]) = rb[p];
            }
            asm volatile("s_waitcnt lgkmcnt(0)" ::: "memory");
        }
    }
    __syncthreads();   // LDS reads done -> reuse lds as 128x128 slab (32 KB)

    // -------- epilogue: gelu+bias -> slab -> coalesced 16B stores (cached) -----
    const float* b1e = b1 + (size_t)e * H;
    float bv[4];
#pragma unroll
    for (int n = 0; n < 4; ++n) bv[n] = b1e[nt * 128 + wn * 64 + n * 16 + r];
#pragma unroll
    for (int m = 0; m < 4; ++m)
#pragma unroll
        for (int j = 0; j < 4; ++j) {
            int lr = wm * 64 + m * 16 + q * 4 + j;
#pragma unroll
            for (int n = 0; n < 4; ++n) {
                int col = wn * 64 + n * 16 + r;
                lds[lr * 128 + col] = f2b(gelu_fast(acc[m][n][j] + bv[n]));
            }
        }
    __syncthreads();
#pragma unroll
    for (int p = 0; p < 8; ++p) {
        int idx = p * 256 + tid;       // 0..2047 = 128 rows x 16 chunks
        int row = idx >> 4;
        int c16 = idx & 15;
        bf16x8 v = *reinterpret_cast<const bf16x8*>(&lds[row * 128 + c16 * 8]);
        *reinterpret_cast<bf16x8*>(&hbuf[(size_t)(p0 + row) * H + nt * 128 + c16 * 8]) = v;
    }
}

// ================= GEMM2: y = h @ W2 + b2 (reg-staged single-buffer) ===========
__global__ __launch_bounds__(256, 3) void gemm2(
    const short* __restrict__ hbuf,
    const short* __restrict__ w2t, const float* __restrict__ b2,
    const int* __restrict__ cnt,
    short* __restrict__ ybuf)
{
    int bid = blockIdx.x;
    int e  = bid & 7;
    int u  = bid >> 3;
    int nt = u & 3;            // nt fastest: same-A blocks adjacent
    int mt = u >> 2;           // 0..63
    int s0, P;
    seg_of(cnt, e, s0, P);
    if (mt * 128 >= P) return;
    int p0 = s0 + mt * 128;

    __shared__ short lds[16384];

    int tid = threadIdx.x;
    int lane = tid & 63;
    int wv = tid >> 6;
    int q = lane >> 4, r = lane & 15;
    int wm = wv >> 1, wn = wv & 1;

    const short* w2e = w2t + (size_t)e * D * H;

    const short* asrc[4];
    const short* bsrc[4];
#pragma unroll
    for (int p = 0; p < 4; ++p) {
        int g = p * 256 + tid;
        int row = g >> 3;
        int slot = (g & 7) ^ (row & 7);
        asrc[p] = hbuf + (size_t)(p0 + row) * H + slot * 8;
        bsrc[p] = w2e + (size_t)(nt * 128 + row) * H + slot * 8;
    }

    f32x4 acc[4][4];
#pragma unroll
    for (int m = 0; m < 4; ++m)
#pragma unroll
        for (int n = 0; n < 4; ++n) acc[m][n] = (f32x4){0.f, 0.f, 0.f, 0.f};

    const int xorv = r & 7;
    const int lw = tid * 8;

    bf16x8 ra[4], rb[4];
#pragma unroll
    for (int p = 0; p < 4; ++p) {
        ra[p] = *reinterpret_cast<const bf16x8*>(asrc[p]);
        rb[p] = *reinterpret_cast<const bf16x8*>(bsrc[p]);
    }
#pragma unroll
    for (int p = 0; p < 4; ++p) {
        *reinterpret_cast<bf16x8*>(&lds[p * 2048 + lw])        = ra[p];
        *reinterpret_cast<bf16x8*>(&lds[8192 + p * 2048 + lw]) = rb[p];
    }
    asm volatile("s_waitcnt lgkmcnt(0)" ::: "memory");

    const int NTT = H / BK;   // 32
    for (int t = 0; t < NTT; ++t) {
        if (t + 1 < NTT) {
            int kk = (t + 1) * BK;
#pragma unroll
            for (int p = 0; p < 4; ++p) {
                ra[p] = *reinterpret_cast<const bf16x8*>(asrc[p] + kk);
                rb[p] = *reinterpret_cast<const bf16x8*>(bsrc[p] + kk);
            }
        }
        __builtin_amdgcn_s_barrier();
        __builtin_amdgcn_sched_barrier(0);

        const char* Ab = (const char*)&lds[0];
        const char* Bb = (const char*)&lds[8192];
#pragma unroll
        for (int ks = 0; ks < 2; ++ks) {
            int sslot = ((ks * 4 + q) ^ xorv) << 4;
            bf16x8 a[4], bb[4];
#pragma unroll
            for (int m = 0; m < 4; ++m)
                a[m] = *(const bf16x8*)(Ab + (wm * 64 + m * 16 + r) * 128 + sslot);
#pragma unroll
            for (int n = 0; n < 4; ++n)
                bb[n] = *(const bf16x8*)(Bb + (wn * 64 + n * 16 + r) * 128 + sslot);
            __builtin_amdgcn_s_setprio(1);
#pragma unroll
            for (int m = 0; m < 4; ++m)
#pragma unroll
                for (int n = 0; n < 4; ++n)
                    acc[m][n] = __builtin_amdgcn_mfma_f32_16x16x32_bf16(a[m], bb[n], acc[m][n], 0, 0, 0);
            __builtin_amdgcn_s_setprio(0);
        }
        __builtin_amdgcn_s_barrier();
        __builtin_amdgcn_sched_barrier(0);
        if (t + 1 < NTT) {
#pragma unroll
            for (int p = 0; p < 4; ++p) {
                *reinterpret_cast<bf16x8*>(&lds[p * 2048 + lw])        = ra[p];
                *reinterpret_cast<bf16x8*>(&lds[8192 + p * 2048 + lw]) = rb[p];
            }
            asm volatile("s_waitcnt lgkmcnt(0)" ::: "memory");
        }
    }
    __syncthreads();

    // -------- epilogue: bias -> slab -> coalesced 16B stores (cached) ----------
    const float* b2e = b2 + (size_t)e * D;
    float bv[4];
#pragma unroll
    for (int n = 0; n < 4; ++n) bv[n] = b2e[nt * 128 + wn * 64 + n * 16 + r];
#pragma unroll
    for (int m = 0; m < 4; ++m)
#pragma unroll
        for (int j = 0; j < 4; ++j) {
            int lr = wm * 64 + m * 16 + q * 4 + j;
#pragma unroll
            for (int n = 0; n < 4; ++n) {
                int col = wn * 64 + n * 16 + r;
                lds[lr * 128 + col] = f2b(acc[m][n][j] + bv[n]);
            }
        }
    __syncthreads();
#pragma unroll
    for (int p = 0; p < 8; ++p) {
        int idx = p * 256 + tid;
        int row = idx >> 4;
        int c16 = idx & 15;
        bf16x8 v = *reinterpret_cast<const bf16x8*>(&lds[row * 128 + c16 * 8]);
        *reinterpret_cast<bf16x8*>(&ybuf[(size_t)(p0 + row) * D + nt * 128 + c16 * 8]) = v;
    }
}

// ================= Combine: out[t] = w0*y[p0] + w1*y[p1] ======================
__global__ __launch_bounds__(256) void combine(
    const short* __restrict__ ybuf, const int* __restrict__ inv,
    const float2* __restrict__ wsel, float* __restrict__ out)
{
    int gid = blockIdx.x * 256 + threadIdx.x;
    int t  = gid >> 7;          // token
    int c4 = (gid & 127) * 4;   // col group
    float2 w = wsel[t];
    int i0 = inv[t * 2], i1 = inv[t * 2 + 1];
    short4 y0 = *reinterpret_cast<const short4*>(ybuf + (size_t)i0 * D + c4);
    short4 y1 = *reinterpret_cast<const short4*>(ybuf + (size_t)i1 * D + c4);
    float4 o;
    o.x = w.x * b2f(y0.x) + w.y * b2f(y1.x);
    o.y = w.x * b2f(y0.y) + w.y * b2f(y1.y);
    o.z = w.x * b2f(y0.z) + w.y * b2f(y1.z);
    o.w = w.x * b2f(y0.w) + w.y * b2f(y1.w);
    *reinterpret_cast<float4*>(out + (size_t)t * D + c4) = o;
}

// ---------------- Round-2 fused MFMA FFN (fallback if ws too small) ------------
#define TMM 64
#define FCC 64
#define XPAD 520
#define HPD 72

__global__ __launch_bounds__(512, 2) void ffn_mfma(
    const float* __restrict__ x,
    const short* __restrict__ w1t, const float* __restrict__ b1,
    const short* __restrict__ w2t, const float* __restrict__ b2,
    const int* __restrict__ cnt, const int* __restrict__ tok_id,
    const float* __restrict__ tok_w,
    float* __restrict__ out)
{
    int b = blockIdx.x;
    int e = b & 7;
    int tile = b >> 3;
    int n = cnt[e];
    int start = tile * TMM;
    if (start >= n) return;
    int nvalid = min(TMM, n - start);

    __shared__ short xs[TMM * XPAD];
    __shared__ short hs[TMM * HPD];
    __shared__ int   stok[TMM];
    __shared__ float sw[TMM];

    int tid = threadIdx.x;
    if (tid < TMM) {
        int tok = 0; float w = 0.f;
        if (tid < nvalid) {
            tok = tok_id[e * NTOK + start + tid];
            w   = tok_w[e * NTOK + start + tid];
        }
        stok[tid] = tok; sw[tid] = w;
    }
    __syncthreads();

    for (int idx = tid; idx < TMM * (D / 4); idx += 512) {
        int row = idx >> 7;
        int c4  = (idx & 127) << 2;
        float4 v = *reinterpret_cast<const float4*>(x + (size_t)stok[row] * D + c4);
        short4 o; o.x = f2b(v.x); o.y = f2b(v.y); o.z = f2b(v.z); o.w = f2b(v.w);
        *reinterpret_cast<short4*>(&xs[row * XPAD + c4]) = o;
    }
    __syncthreads();

    const int lane = tid & 63, wave = tid >> 6;
    const int wm = wave >> 2, wn = wave & 3;
    const int q = lane >> 4,  r = lane & 15;

    const short* w1e = w1t + (size_t)e * H * D;
    const short* w2e = w2t + (size_t)e * D * H;
    const float* b1e = b1 + (size_t)e * H;
    const float* b2e = b2 + (size_t)e * D;

    f32x4 acc[2][8];
#pragma unroll
    for (int i = 0; i < 2; ++i)
#pragma unroll
        for (int j = 0; j < 8; ++j) acc[i][j] = (f32x4){0.f, 0.f, 0.f, 0.f};

    for (int fc = 0; fc < H; fc += FCC) {
        int f = fc + wn * 16 + r;
        float b1f = b1e[f];
        f32x4 h0 = {b1f, b1f, b1f, b1f};
        f32x4 h1 = h0;
        const short* wrow = w1e + (size_t)f * D;
        const short* a0p = &xs[(wm * 32 + r) * XPAD + q * 8];
        const short* a1p = a0p + 16 * XPAD;
#pragma unroll
        for (int ks = 0; ks < 16; ++ks) {
            bf16x8 bfr = *reinterpret_cast<const bf16x8*>(wrow + ks * 32 + q * 8);
            bf16x8 a0  = *reinterpret_cast<const bf16x8*>(a0p + ks * 32);
            bf16x8 a1  = *reinterpret_cast<const bf16x8*>(a1p + ks * 32);
            h0 = __builtin_amdgcn_mfma_f32_16x16x32_bf16(a0, bfr, h0, 0, 0, 0);
            h1 = __builtin_amdgcn_mfma_f32_16x16x32_bf16(a1, bfr, h1, 0, 0, 0);
        }
        {
            int c = wn * 16 + r;
#pragma unroll
            for (int j = 0; j < 4; ++j) {
                hs[(wm * 32 + q * 4 + j) * HPD + c]      = f2b(gelu_exact(h0[j]));
                hs[(wm * 32 + 16 + q * 4 + j) * HPD + c] = f2b(gelu_exact(h1[j]));
            }
        }
        __syncthreads();
#pragma unroll
        for (int ks = 0; ks < 2; ++ks) {
            bf16x8 a20 = *reinterpret_cast<const bf16x8*>(&hs[(wm * 32 + r) * HPD + ks * 32 + q * 8]);
            bf16x8 a21 = *reinterpret_cast<const bf16x8*>(&hs[(wm * 32 + 16 + r) * HPD + ks * 32 + q * 8]);
#pragma unroll
            for (int nr = 0; nr < 8; ++nr) {
                int dout = wn * 128 + nr * 16 + r;
                bf16x8 bfr = *reinterpret_cast<const bf16x8*>(
                    w2e + (size_t)dout * H + fc + ks * 32 + q * 8);
                acc[0][nr] = __builtin_amdgcn_mfma_f32_16x16x32_bf16(a20, bfr, acc[0][nr], 0, 0, 0);
                acc[1][nr] = __builtin_amdgcn_mfma_f32_16x16x32_bf16(a21, bfr, acc[1][nr], 0, 0, 0);
            }
        }
        __syncthreads();
    }

#pragma unroll
    for (int mrep = 0; mrep < 2; ++mrep) {
#pragma unroll
        for (int j = 0; j < 4; ++j) {
            int rl = wm * 32 + mrep * 16 + q * 4 + j;
            if (rl < nvalid) {
                float w = sw[rl];
                if (w != 0.f) {
                    float* orow = out + (size_t)stok[rl] * D;
#pragma unroll
                    for (int nr = 0; nr < 8; ++nr) {
                        int dout = wn * 128 + nr * 16 + r;
                        f32x4 a = acc[mrep][nr];
                        atomicAdd(&orow[dout], w * (a[j] + b2e[dout]));
                    }
                }
            }
        }
    }
}

extern "C" void kernel_launch(void* const* d_in, const int* in_sizes, int n_in,
                              void* d_out, int out_size, void* d_ws, size_t ws_size,
                              hipStream_t stream) {
    const float* x  = (const float*)d_in[0];
    const float* ts = (const float*)d_in[1];
    const float* gw = (const float*)d_in[2];
    const float* gb = (const float*)d_in[3];
    const float* w1 = (const float*)d_in[4];
    const float* b1 = (const float*)d_in[5];
    const float* w2 = (const float*)d_in[6];
    const float* b2 = (const float*)d_in[7];
    float* out = (float*)d_out;

    // ws layout (bytes):
    // cnt@0 | tok_id@1024 (256K) | tok_w@263168 (256K) |
    // pad_tok@525312 (68K) | pad_w@594944 (68K) | sel@665600 (32K) |
    // wsel@700416 (64K) | inv@765952 (64K) | xbf@1M (8M) |
    // w1t@9437184 (16.78M) | w2t@26214400 (16.78M) | hbuf@42991616 (71.3M)
    // ybuf@1M (17.83M) overlays xbf+w1t — both dead after gemm1.
    int*    cnt     = (int*)d_ws;
    int*    tok_id  = (int*)((char*)d_ws + 1024);
    float*  tok_w   = (float*)((char*)d_ws + 263168);
    int*    pad_tok = (int*)((char*)d_ws + 525312);
    float*  pad_w   = (float*)((char*)d_ws + 594944);
    int*    sel     = (int*)((char*)d_ws + 665600);
    float2* wsel    = (float2*)((char*)d_ws + 700416);
    int*    inv     = (int*)((char*)d_ws + 765952);
    short*  xbf     = (short*)((char*)d_ws + 1048576);
    short*  w1t     = (short*)((char*)d_ws + 9437184);
    short*  w2t     = (short*)((char*)d_ws + 26214400);
    short*  hbuf    = (short*)((char*)d_ws + 42991616);
    short*  ybuf    = (short*)((char*)d_ws + 1048576);   // overlays xbf+w1t
    const size_t ws_need = 114294784;

    hipMemsetAsync(cnt, 0, 64, stream);

    if (ws_size >= ws_need) {
        router_score<<<NTOK / 4, 256, 0, stream>>>(x, ts, gw, gb, sel, wsel, xbf);
        scatter_tokens<<<NTOK / 256, 256, 0, stream>>>(sel, wsel, cnt, tok_id, tok_w);
        transpose_pad<<<dim3(8, 32, 2 * E + 1), 256, 0, stream>>>(
            w1, w1t, w2, w2t, cnt, sel, tok_id, tok_w, pad_tok, pad_w, inv);
        gemm1<<<E * 64 * 16, 256, 0, stream>>>(xbf, w1t, b1, cnt, pad_tok, hbuf);
        gemm2<<<E * 64 * 4, 256, 0, stream>>>(hbuf, w2t, b2, cnt, ybuf);
        combine<<<NTOK * (D / 4) / 256, 256, 0, stream>>>(ybuf, inv, wsel, out);
    } else {
        // fallback: round-2 layout (w1t@1M, w2t after)
        hipMemsetAsync(out, 0, (size_t)out_size * sizeof(float), stream);
        short* w1t_f = (short*)((char*)d_ws + (1u << 20));
        short* w2t_f = w1t_f + (size_t)E * D * H;
        router_kernel<<<NTOK / 256, 256, 0, stream>>>(x, ts, gw, gb, cnt, tok_id, tok_w);
        transpose_pad<<<dim3(8, 32, 2 * E), 256, 0, stream>>>(
            w1, w1t_f, w2, w2t_f, cnt, nullptr, nullptr, nullptr,
            nullptr, nullptr, nullptr);
        ffn_mfma<<<(NTOK / TMM) * E, 512, 0, stream>>>(
            x, w1t_f, b1, w2t_f, b2, cnt, tok_id, tok_w, out);
    }
}